// Round 12
// baseline (1261.294 us; speedup 1.0000x reference)
//
#include <hip/hip_runtime.h>
#include <math.h>

#define TT 1024
#define DIN 128
#define HH 64
#define NN 16
#define EE 32
#define LL 3
#define BB 32
#define LOG2E 1.4426950408889634f

__device__ __forceinline__ float siluf(float x) { return x / (1.f + __expf(-x)); }

typedef __attribute__((ext_vector_type(8))) short bf16x8;
typedef __attribute__((ext_vector_type(4))) float f32x4;

// split fp32 into bf16 hi + bf16 lo (truncation; a ~= hi + lo, err ~2^-16 rel)
__device__ __forceinline__ void split2(float x, ushort& hi, ushort& lo) {
  unsigned u = __float_as_uint(x);
  hi = (ushort)(u >> 16);
  float rem = x - __uint_as_float((u >> 16) << 16);
  lo = (ushort)(__float_as_uint(rem) >> 16);
}

// ---------------- K1: xz = h @ inW^T via split-bf16 MFMA ----------------
// A-tile (h) staged+split ONCE per block; loops over the 4 n-tiles of W.
// l==0: A-tile computed on the fly from x*inpW+inpb (k_init folded in).
__global__ __launch_bounds__(256) void k_xz(
    const float* __restrict__ x0, const float* __restrict__ x1,
    const float* __restrict__ x2, const float* __restrict__ x3,
    const float* __restrict__ h, const float* __restrict__ inprojW,
    const float* __restrict__ inpW, const float* __restrict__ inpb,
    float* __restrict__ xr, float* __restrict__ zb, int br0, int l) {
  __shared__ __align__(16) ushort Hh[64][72], Hl[64][72];  // h tile [t][k]
  __shared__ __align__(16) ushort Wh[64][72], Wl[64][72];  // W tile [n][k]
  const int tid = threadIdx.x;
  const int b  = blockIdx.y;
  const int t0 = blockIdx.x * 64;
  const int br = br0 + (b >> 5);
  const float* Hg = h + ((size_t)b * TT + t0) * HH;
  const int row = tid >> 2, c0 = (tid & 3) * 16;
  {
    float xv = 0.f;
    if (l == 0) {
      int bb = b & 31;
      const float* xp = (br == 0) ? x0 : (br == 1) ? x1 : (br == 2) ? x2 : x3;
      xv = xp[bb * TT + t0 + row];
    }
    #pragma unroll
    for (int q = 0; q < 4; ++q) {
      float4 hv;
      if (l == 0) {
        float4 w4 = *(const float4*)(inpW + br * HH + c0 + q * 4);
        float4 b4 = *(const float4*)(inpb + br * HH + c0 + q * 4);
        hv.x = xv * w4.x + b4.x; hv.y = xv * w4.y + b4.y;
        hv.z = xv * w4.z + b4.z; hv.w = xv * w4.w + b4.w;
      } else {
        hv = *(const float4*)(Hg + (size_t)row * HH + c0 + q * 4);
      }
      ushort h0,h1,h2,h3,l0,l1,l2,l3;
      split2(hv.x,h0,l0); split2(hv.y,h1,l1); split2(hv.z,h2,l2); split2(hv.w,h3,l3);
      *(ushort4*)&Hh[row][c0 + q*4] = make_ushort4(h0,h1,h2,h3);
      *(ushort4*)&Hl[row][c0 + q*4] = make_ushort4(l0,l1,l2,l3);
    }
  }
  const int wave = tid >> 6, lane = tid & 63;
  const int quad = lane >> 4, l16 = lane & 15;
  const int nsub = (wave & 1) * 32, tsub = (wave >> 1) * 32;
  for (int n0 = 0; n0 < 2 * DIN; n0 += 64) {
    const float* Wg = inprojW + (size_t)((br * LL + l) * 2 * DIN + n0) * HH;
    {
      #pragma unroll
      for (int q = 0; q < 4; ++q) {
        float4 wv = *(const float4*)(Wg + (size_t)row * HH + c0 + q * 4);
        ushort h0,h1,h2,h3,l0,l1,l2,l3;
        split2(wv.x,h0,l0); split2(wv.y,h1,l1); split2(wv.z,h2,l2); split2(wv.w,h3,l3);
        *(ushort4*)&Wh[row][c0 + q*4] = make_ushort4(h0,h1,h2,h3);
        *(ushort4*)&Wl[row][c0 + q*4] = make_ushort4(l0,l1,l2,l3);
      }
    }
    __syncthreads();
    f32x4 acc[2][2] = {};   // [n-frag][t-frag]
    #pragma unroll
    for (int k0 = 0; k0 < 64; k0 += 32) {
      bf16x8 Ah[2], Al[2], Bh[2], Bl[2];
      #pragma unroll
      for (int i = 0; i < 2; ++i) {
        Ah[i] = *(const bf16x8*)&Wh[nsub + i*16 + l16][k0 + quad*8];
        Al[i] = *(const bf16x8*)&Wl[nsub + i*16 + l16][k0 + quad*8];
        Bh[i] = *(const bf16x8*)&Hh[tsub + i*16 + l16][k0 + quad*8];
        Bl[i] = *(const bf16x8*)&Hl[tsub + i*16 + l16][k0 + quad*8];
      }
      #pragma unroll
      for (int i = 0; i < 2; ++i)
        #pragma unroll
        for (int j = 0; j < 2; ++j) {
          acc[i][j] = __builtin_amdgcn_mfma_f32_16x16x32_bf16(Ah[i], Bh[j], acc[i][j], 0, 0, 0);
          acc[i][j] = __builtin_amdgcn_mfma_f32_16x16x32_bf16(Ah[i], Bl[j], acc[i][j], 0, 0, 0);
          acc[i][j] = __builtin_amdgcn_mfma_f32_16x16x32_bf16(Al[i], Bh[j], acc[i][j], 0, 0, 0);
        }
    }
    // D layout: col(t) = lane&15, row(n) = quad*4 + reg
    #pragma unroll
    for (int i = 0; i < 2; ++i) {
      #pragma unroll
      for (int r = 0; r < 4; ++r) {
        int n = n0 + nsub + i*16 + quad*4 + r;
        float* dst = (n < DIN) ? (xr + ((size_t)b * DIN + n) * TT)
                               : (zb + ((size_t)b * DIN + (n - DIN)) * TT);
        #pragma unroll
        for (int j = 0; j < 2; ++j)
          dst[t0 + tsub + j*16 + l16] = acc[i][j][r];
      }
    }
    __syncthreads();  // protect Wh/Wl before next n-tile restages
  }
}

// ---- K3: fused conv+silu into x_dbl GEMM (split-bf16 MFMA); writes u; dt epilogue ----
// W pre-split once per k0 into bf16 LDS (kills 4x-redundant per-wave splits);
// As2 padded to 70 (2-way banks = free) with float2 writes for alignment.
__global__ __launch_bounds__(256) void k_xdbl(
    const float* __restrict__ xr, const float* __restrict__ convW,
    const float* __restrict__ convb, const float* __restrict__ xprojW,
    const float* __restrict__ dtW, const float* __restrict__ dtb,
    float* __restrict__ u, float* __restrict__ dt,
    float* __restrict__ Bm, float* __restrict__ Cm,
    int br0, int l) {
  __shared__ __align__(16) float Xr[16][72];
  __shared__ __align__(16) float As2[32][70];      // u tile, fp32 [k][t]
  __shared__ __align__(16) ushort Wh2[48][40], Wl2[48][40];  // W bf16 [n][k]
  __shared__ __align__(16) float Xs[40][68];
  const int tid = threadIdx.x;
  const int b  = blockIdx.y;
  const int t0 = blockIdx.x * 64;
  const int br = br0 + (b >> 5);
  const float* W = xprojW + (size_t)((br * LL + l) * 36) * DIN;
  const int rowk = tid >> 4, c4 = tid & 15;
  const int wave = tid >> 6, lane = tid & 63;
  const int quad = lane >> 4, l16 = lane & 15;
  const int tw = wave * 16;            // wave's t-offset
  f32x4 acc[3] = {};                   // 3 n-frags (n = 0..47), t = tw..tw+15
  for (int k0 = 0; k0 < DIN; k0 += 32) {
    #pragma unroll
    for (int ks = 0; ks < 32; ks += 16) {
      __syncthreads();
      {
        const float* src = xr + ((size_t)b * DIN + k0 + ks + rowk) * TT + t0;
        *(float4*)&Xr[rowk][4 + c4 * 4] = *(const float4*)(src + c4 * 4);
        if (tid < 16) {
          float4 hv = make_float4(0.f, 0.f, 0.f, 0.f);
          if (t0 > 0) hv = *(const float4*)(xr + ((size_t)b * DIN + k0 + ks + tid) * TT + t0 - 4);
          *(float4*)&Xr[tid][0] = hv;
        }
      }
      __syncthreads();
      {
        int d = k0 + ks + rowk;
        const float* w = convW + (size_t)((br * LL + l) * DIN + d) * 4;
        float w0 = w[0], w1 = w[1], w2 = w[2], w3 = w[3];
        float cb = convb[(br * LL + l) * DIN + d];
        int i0 = c4 * 4;
        float o[4];
        #pragma unroll
        for (int q = 0; q < 4; ++q) {
          int j = i0 + q;
          float a = Xr[rowk][j+1]*w0 + Xr[rowk][j+2]*w1 + Xr[rowk][j+3]*w2 + Xr[rowk][j+4]*w3 + cb;
          o[q] = siluf(a);
        }
        *(float2*)&As2[ks + rowk][i0]     = make_float2(o[0], o[1]);
        *(float2*)&As2[ks + rowk][i0 + 2] = make_float2(o[2], o[3]);
        *(float4*)(u + ((size_t)b * DIN + d) * TT + t0 + i0) =
            make_float4(o[0], o[1], o[2], o[3]);
      }
    }
    // stage + pre-split W chunk [48 n][32 k] (n >= 36 zeroed)
    for (int idx = tid; idx < 1536; idx += 256) {
      int jj = idx >> 5, kk = idx & 31;
      float v = (jj < 36) ? W[(size_t)jj * DIN + k0 + kk] : 0.f;
      ushort hi, lo; split2(v, hi, lo);
      Wh2[jj][kk] = hi; Wl2[jj][kk] = lo;
    }
    __syncthreads();
    // MFMA: A = W (rows n, bf16 pre-split), B = u (split in-register)
    ushort bh[8], bl[8];
    #pragma unroll
    for (int j = 0; j < 8; ++j) {
      float v = As2[quad * 8 + j][tw + l16];
      split2(v, bh[j], bl[j]);
    }
    bf16x8 Bh = *(bf16x8*)bh, Bl = *(bf16x8*)bl;
    #pragma unroll
    for (int nf = 0; nf < 3; ++nf) {
      bf16x8 Whf = *(const bf16x8*)&Wh2[nf * 16 + l16][quad * 8];
      bf16x8 Wlf = *(const bf16x8*)&Wl2[nf * 16 + l16][quad * 8];
      acc[nf] = __builtin_amdgcn_mfma_f32_16x16x32_bf16(Whf, Bh, acc[nf], 0, 0, 0);
      acc[nf] = __builtin_amdgcn_mfma_f32_16x16x32_bf16(Whf, Bl, acc[nf], 0, 0, 0);
      acc[nf] = __builtin_amdgcn_mfma_f32_16x16x32_bf16(Wlf, Bh, acc[nf], 0, 0, 0);
    }
  }
  __syncthreads();
  // D layout: col(t) = l16, row(n) = quad*4 + r  ->  Xs[n][t]
  #pragma unroll
  for (int nf = 0; nf < 3; ++nf) {
    #pragma unroll
    for (int r = 0; r < 4; ++r) {
      int n = nf * 16 + quad * 4 + r;
      if (n < 40) Xs[n][tw + l16] = acc[nf][r];
    }
  }
  __syncthreads();
  {
    int n = tid >> 4, i0 = (tid & 15) * 4;
    *(float4*)(Bm + ((size_t)b * NN + n) * TT + t0 + i0) = *(float4*)&Xs[4 + n][i0];
    *(float4*)(Cm + ((size_t)b * NN + n) * TT + t0 + i0) = *(float4*)&Xs[20 + n][i0];
  }
  {
    int d = tid >> 1, half = tid & 1;
    const float* wd = dtW + (size_t)((br * LL + l) * DIN + d) * 4;
    float w0 = wd[0], w1 = wd[1], w2 = wd[2], w3 = wd[3];
    float bias = dtb[(br * LL + l) * DIN + d];
    float* dtp = dt + ((size_t)b * DIN + d) * TT + t0 + half * 32;
    #pragma unroll
    for (int g8 = 0; g8 < 8; ++g8) {
      float o[4];
      #pragma unroll
      for (int q = 0; q < 4; ++q) {
        int i = half * 32 + g8 * 4 + q;
        float s = Xs[0][i]*w0 + Xs[1][i]*w1 + Xs[2][i]*w2 + Xs[3][i]*w3 + bias;
        float e = __expf(-fabsf(s));
        o[q] = fmaxf(s, 0.f) + __logf(1.f + e);
      }
      *(float4*)(dtp + g8*4) = make_float4(o[0], o[1], o[2], o[3]);
    }
  }
}

// ---- K4a: local chunk scan (chunk=64). Emits y_intra (g), Hloc, sdt (chunk dt-sums).
// Ac pre-scaled by log2(e): dA = exp2f(dt*Ac) saves one mul per exp in the hot loop.
__global__ __launch_bounds__(256) void k_scan1(
    const float* __restrict__ dtc, const float* __restrict__ u,
    const float* __restrict__ Bm, const float* __restrict__ Cm,
    const float* __restrict__ A_log, const float* __restrict__ D_skip,
    float* __restrict__ Hloc, float* __restrict__ g, float* __restrict__ sdt,
    int br0, int l) {
  __shared__ __align__(16) float Bl[16][68];
  __shared__ __align__(16) float Cl[16][68];
  const int bx  = blockIdx.x;
  const int b   = bx >> 5;
  const int rem = bx & 31;
  const int c   = rem >> 1;
  const int dh  = rem & 1;
  const int tid = threadIdx.x;
  {
    int row = tid >> 4, cc = (tid & 15) * 4;
    *(float4*)&Bl[row][cc] = *(const float4*)(Bm + ((size_t)b * NN + row) * TT + c * 64 + cc);
    *(float4*)&Cl[row][cc] = *(const float4*)(Cm + ((size_t)b * NN + row) * TT + c * 64 + cc);
  }
  __syncthreads();
  const int d  = dh * 64 + (tid >> 2);
  const int n0 = (tid & 3) * 4;
  const int br = br0 + (b >> 5);
  const int wbase = (br * LL + l) * DIN + d;
  float Ac[4];
  #pragma unroll
  for (int j = 0; j < 4; ++j) Ac[j] = -__expf(A_log[(size_t)wbase * NN + n0 + j]) * LOG2E;
  float Dp = D_skip[wbase];
  const float* dtp = dtc + ((size_t)b * DIN + d) * TT + c * 64;
  const float* up = u + ((size_t)b * DIN + d) * TT + c * 64;
  float* gp = g + ((size_t)b * DIN + d) * TT + c * 64;
  float hst[4] = {0.f, 0.f, 0.f, 0.f};
  float sd = 0.f;
  for (int t0 = 0; t0 < 64; t0 += 8) {
    float4 dq0 = *(const float4*)(dtp + t0);
    float4 dq1 = *(const float4*)(dtp + t0 + 4);
    float4 uq0 = *(const float4*)(up + t0);
    float4 uq1 = *(const float4*)(up + t0 + 4);
    float dts[8] = {dq0.x, dq0.y, dq0.z, dq0.w, dq1.x, dq1.y, dq1.z, dq1.w};
    float us[8]  = {uq0.x, uq0.y, uq0.z, uq0.w, uq1.x, uq1.y, uq1.z, uq1.w};
    float Bs[4][8], Cr[4][8];
    #pragma unroll
    for (int j = 0; j < 4; ++j) {
      float4 b0 = *(const float4*)&Bl[n0 + j][t0];
      float4 b1 = *(const float4*)&Bl[n0 + j][t0 + 4];
      Bs[j][0]=b0.x; Bs[j][1]=b0.y; Bs[j][2]=b0.z; Bs[j][3]=b0.w;
      Bs[j][4]=b1.x; Bs[j][5]=b1.y; Bs[j][6]=b1.z; Bs[j][7]=b1.w;
      float4 c0 = *(const float4*)&Cl[n0 + j][t0];
      float4 c1 = *(const float4*)&Cl[n0 + j][t0 + 4];
      Cr[j][0]=c0.x; Cr[j][1]=c0.y; Cr[j][2]=c0.z; Cr[j][3]=c0.w;
      Cr[j][4]=c1.x; Cr[j][5]=c1.y; Cr[j][6]=c1.z; Cr[j][7]=c1.w;
    }
    float yo[8];
    #pragma unroll
    for (int s = 0; s < 8; ++s) {
      float dtv = dts[s], uv = us[s];
      sd += dtv;
      float du = dtv * uv;
      float acc = 0.f;
      #pragma unroll
      for (int j = 0; j < 4; ++j) {
        float dA = exp2f(dtv * Ac[j]);
        hst[j] = dA * hst[j] + du * Bs[j][s];
        acc += hst[j] * Cr[j][s];
      }
      acc += __shfl_xor(acc, 1, 4);
      acc += __shfl_xor(acc, 2, 4);
      yo[s] = acc + Dp * uv;
    }
    if ((tid & 3) == 0) {
      *(float4*)(gp + t0)     = make_float4(yo[0], yo[1], yo[2], yo[3]);
      *(float4*)(gp + t0 + 4) = make_float4(yo[4], yo[5], yo[6], yo[7]);
    }
  }
  *(float4*)(Hloc + (((size_t)b * DIN + d) * 16 + c) * 16 + n0) =
      make_float4(hst[0], hst[1], hst[2], hst[3]);
  if ((tid & 3) == 0) sdt[((size_t)b * DIN + d) * 16 + c] = sd;
}

// ---- K4c: combine (from Hloc + sdt) + parallel correction.
// cd recomputed from dt via in-LDS prefix (same serial order as scan1).
__global__ __launch_bounds__(256) void k_scan2(
    const float* __restrict__ dtc, const float* __restrict__ Cm,
    const float* __restrict__ A_log, const float* __restrict__ Hloc,
    const float* __restrict__ sdt, float* __restrict__ g, int br0, int l) {
  __shared__ __align__(16) float Cl[16][68];
  __shared__ __align__(16) float Dl[32][68];
  __shared__ __align__(16) float HinL[32][16];
  const int bx  = blockIdx.x;
  const int b   = bx >> 6;
  const int rem = bx & 63;
  const int c   = rem >> 2;
  const int dq  = rem & 3;
  const int tid = threadIdx.x;
  const int br  = br0 + (b >> 5);
  if (c == 0) return;  // h_in = 0 -> correction adds nothing
  {
    int row = tid >> 4, cc = (tid & 15) * 4;
    *(float4*)&Cl[row][cc] = *(const float4*)(Cm + ((size_t)b * NN + row) * TT + c * 64 + cc);
  }
  const int dloc = tid >> 3, tg = tid & 7;
  const int d  = dq * 32 + dloc;
  // stage this block's dt chunk [32 d][64 t]
  {
    const float* dp = dtc + ((size_t)b * DIN + d) * TT + c * 64 + tg * 8;
    *(float4*)&Dl[dloc][tg * 8]     = *(const float4*)dp;
    *(float4*)&Dl[dloc][tg * 8 + 4] = *(const float4*)(dp + 4);
  }
  // combine phase: h_in for this chunk, threads = (dloc 32) x (n-pair 8)
  {
    int n0 = (tid & 7) * 2;
    int wbase = (br * LL + l) * DIN + d;
    float a0 = -__expf(A_log[(size_t)wbase * NN + n0]) * LOG2E;
    float a1 = -__expf(A_log[(size_t)wbase * NN + n0 + 1]) * LOG2E;
    float h0 = 0.f, h1 = 0.f;
    const float* sp  = sdt + ((size_t)b * DIN + d) * 16;
    const float* hlb = Hloc + ((size_t)b * DIN + d) * 256;
    for (int cc = 0; cc < c; ++cc) {
      float sdv = sp[cc];
      float2 hl = *(const float2*)(hlb + cc * 16 + n0);
      h0 = exp2f(a0 * sdv) * h0 + hl.x;
      h1 = exp2f(a1 * sdv) * h1 + hl.y;
    }
    HinL[dloc][n0] = h0;
    HinL[dloc][n0 + 1] = h1;
  }
  __syncthreads();
  // recompute cd for this thread's 8 t's (serial ascending, same order as scan1)
  float cd8[8];
  {
    float run = 0.f;
    for (int t = 0; t < tg * 8; ++t) run += Dl[dloc][t];
    #pragma unroll
    for (int s = 0; s < 8; ++s) { run += Dl[dloc][tg * 8 + s]; cd8[s] = run; }
  }
  const float* al = A_log + (size_t)((br * LL + l) * DIN + d) * NN;
  float Ac16[16];
  #pragma unroll
  for (int n = 0; n < 16; ++n) Ac16[n] = -__expf(al[n]) * LOG2E;
  size_t off = ((size_t)b * DIN + d) * TT + c * 64 + tg * 8;
  float* gp = g + off;
  float4 y0 = *(float4*)gp;
  float4 y1 = *(float4*)(gp + 4);
  float y8[8] = {y0.x, y0.y, y0.z, y0.w, y1.x, y1.y, y1.z, y1.w};
  const int tbase = tg * 8;
  #pragma unroll
  for (int n = 0; n < 16; ++n) {
    float hv = HinL[dloc][n];
    float an = Ac16[n];
    #pragma unroll
    for (int s = 0; s < 8; ++s)
      y8[s] += Cl[n][tbase + s] * exp2f(an * cd8[s]) * hv;
  }
  *(float4*)gp       = make_float4(y8[0], y8[1], y8[2], y8[3]);
  *(float4*)(gp + 4) = make_float4(y8[4], y8[5], y8[6], y8[7]);
}

// ---------------- K5: h = (y * silu(z)) @ outW^T via split-bf16 MFMA ----------------
__global__ __launch_bounds__(256) void k_out(
    const float* __restrict__ graw, const float* __restrict__ zb,
    const float* __restrict__ outW, float* __restrict__ h, int br0, int l) {
  __shared__ __align__(16) ushort Ah_[64][72], Al_[64][72];  // outW tile [hh][k]
  __shared__ __align__(16) ushort Bh_[64][72], Bl_[64][72];  // act tile [d][t]
  const int tid = threadIdx.x;
  const int b  = blockIdx.y;
  const int t0 = blockIdx.x * 64;
  const int br = br0 + (b >> 5);
  const float* Wg = outW + (size_t)((br * LL + l) * HH) * DIN;
  const int wave = tid >> 6, lane = tid & 63;
  const int quad = lane >> 4, l16 = lane & 15;
  const int hsub = (wave & 1) * 32, tsub = (wave >> 1) * 32;
  f32x4 acc[2][2] = {};   // [hh-frag][t-frag]
  for (int k0 = 0; k0 < DIN; k0 += 64) {
    __syncthreads();
    {
      int row = tid >> 2, c0 = (tid & 3) * 16;
      #pragma unroll
      for (int q = 0; q < 4; ++q) {
        float4 wv = *(const float4*)(Wg + (size_t)row * DIN + k0 + c0 + q * 4);
        ushort h0,h1,h2,h3,l0,l1,l2,l3;
        split2(wv.x,h0,l0); split2(wv.y,h1,l1); split2(wv.z,h2,l2); split2(wv.w,h3,l3);
        *(ushort4*)&Ah_[row][c0 + q*4] = make_ushort4(h0,h1,h2,h3);
        *(ushort4*)&Al_[row][c0 + q*4] = make_ushort4(l0,l1,l2,l3);
        size_t off = ((size_t)b * DIN + k0 + row) * TT + t0 + c0 + q * 4;
        float4 gv = *(const float4*)(graw + off);
        float4 zv = *(const float4*)(zb + off);
        float a0 = gv.x * siluf(zv.x), a1 = gv.y * siluf(zv.y);
        float a2 = gv.z * siluf(zv.z), a3 = gv.w * siluf(zv.w);
        split2(a0,h0,l0); split2(a1,h1,l1); split2(a2,h2,l2); split2(a3,h3,l3);
        *(ushort4*)&Bh_[row][c0 + q*4] = make_ushort4(h0,h1,h2,h3);
        *(ushort4*)&Bl_[row][c0 + q*4] = make_ushort4(l0,l1,l2,l3);
      }
    }
    __syncthreads();
    #pragma unroll
    for (int kk = 0; kk < 64; kk += 32) {
      bf16x8 Ahf[2], Alf[2], Bhf[2], Blf[2];
      #pragma unroll
      for (int i = 0; i < 2; ++i) {
        Ahf[i] = *(const bf16x8*)&Ah_[hsub + i*16 + l16][kk + quad*8];
        Alf[i] = *(const bf16x8*)&Al_[hsub + i*16 + l16][kk + quad*8];
        Bhf[i] = *(const bf16x8*)&Bh_[tsub + i*16 + l16][kk + quad*8];
        Blf[i] = *(const bf16x8*)&Bl_[tsub + i*16 + l16][kk + quad*8];
      }
      #pragma unroll
      for (int i = 0; i < 2; ++i)
        #pragma unroll
        for (int j = 0; j < 2; ++j) {
          acc[i][j] = __builtin_amdgcn_mfma_f32_16x16x32_bf16(Ahf[i], Bhf[j], acc[i][j], 0, 0, 0);
          acc[i][j] = __builtin_amdgcn_mfma_f32_16x16x32_bf16(Ahf[i], Blf[j], acc[i][j], 0, 0, 0);
          acc[i][j] = __builtin_amdgcn_mfma_f32_16x16x32_bf16(Alf[i], Bhf[j], acc[i][j], 0, 0, 0);
        }
    }
  }
  #pragma unroll
  for (int i = 0; i < 2; ++i) {
    int hh0 = hsub + i*16 + quad*4;
    #pragma unroll
    for (int j = 0; j < 2; ++j) {
      int t = t0 + tsub + j*16 + l16;
      *(f32x4*)(h + ((size_t)b * TT + t) * HH + hh0) = acc[i][j];
    }
  }
}

// ---------------- K6: ze = tanh(h @ outp_W^T + outp_b) ----------------
__global__ __launch_bounds__(256) void k_ze(
    const float* __restrict__ h, const float* __restrict__ outpW,
    const float* __restrict__ outpb, float* __restrict__ ze, int br0) {
  __shared__ __align__(16) float As[16][132];
  __shared__ __align__(16) float Ws[16][36];
  __shared__ __align__(16) float Cs[128][36];
  const int tid = threadIdx.x;
  const int b  = blockIdx.y;
  const int t0 = blockIdx.x * 128;
  const int br = br0 + (b >> 5);
  const float* W = outpW + (size_t)br * EE * HH;
  float acc[4][4] = {};
  const int ti = tid & 31, ni = tid >> 5;
  for (int k0 = 0; k0 < HH; k0 += 16) {
    __syncthreads();
    {
      int i = tid >> 1, kq = (tid & 1) * 8;
      const float* src = h + ((size_t)b * TT + t0 + i) * HH + k0 + kq;
      float4 a0 = *(const float4*)src;
      float4 a1 = *(const float4*)(src + 4);
      As[kq+0][i]=a0.x; As[kq+1][i]=a0.y; As[kq+2][i]=a0.z; As[kq+3][i]=a0.w;
      As[kq+4][i]=a1.x; As[kq+5][i]=a1.y; As[kq+6][i]=a1.z; As[kq+7][i]=a1.w;
    }
    for (int idx = tid; idx < 512; idx += 256) {
      int jj = idx >> 4, kk = idx & 15;
      Ws[kk][jj] = W[(size_t)jj * HH + k0 + kk];
    }
    __syncthreads();
    #pragma unroll
    for (int kk = 0; kk < 16; ++kk) {
      float4 a = *(const float4*)&As[kk][ti * 4];
      float4 w = *(const float4*)&Ws[kk][ni * 4];
      acc[0][0] += a.x*w.x; acc[0][1] += a.x*w.y; acc[0][2] += a.x*w.z; acc[0][3] += a.x*w.w;
      acc[1][0] += a.y*w.x; acc[1][1] += a.y*w.y; acc[1][2] += a.y*w.z; acc[1][3] += a.y*w.w;
      acc[2][0] += a.z*w.x; acc[2][1] += a.z*w.y; acc[2][2] += a.z*w.z; acc[2][3] += a.z*w.w;
      acc[3][0] += a.w*w.x; acc[3][1] += a.w*w.y; acc[3][2] += a.w*w.z; acc[3][3] += a.w*w.w;
    }
  }
  __syncthreads();
  float bj[4];
  #pragma unroll
  for (int c = 0; c < 4; ++c) bj[c] = outpb[br * EE + ni*4 + c];
  #pragma unroll
  for (int r = 0; r < 4; ++r)
    #pragma unroll
    for (int c = 0; c < 4; ++c)
      Cs[ti*4+r][ni*4+c] = tanhf(acc[r][c] + bj[c]);
  __syncthreads();
  int i = tid >> 1, j16 = (tid & 1) * 16;
  float* dst = ze + (((size_t)(br0 * 32 + b)) * TT + t0 + i) * EE + j16;
  #pragma unroll
  for (int q = 0; q < 4; ++q)
    *(float4*)(dst + q*4) = *(float4*)&Cs[i][j16 + q*4];
}

// ---------------- K7: hyperbolic combine ----------------
__device__ __forceinline__ void mobius_add32(const float* x, const float* y, float* o) {
  float x2 = 0.f, y2 = 0.f, xy = 0.f;
  #pragma unroll
  for (int i = 0; i < 32; ++i) { x2 += x[i]*x[i]; y2 += y[i]*y[i]; xy += x[i]*y[i]; }
  float ca  = 1.f + 2.f*xy + y2;
  float cb  = 1.f - x2;
  float den = 1.f + 2.f*xy + x2*y2;
  float inv = 1.f / fmaxf(den, 1e-15f);
  #pragma unroll
  for (int i = 0; i < 32; ++i) o[i] = (ca*x[i] + cb*y[i]) * inv;
}

__global__ __launch_bounds__(256) void k_hyper(const float* __restrict__ ze,
                                               float* __restrict__ out) {
  int idx = blockIdx.x * 256 + threadIdx.x;
  int b = idx >> 10, t = idx & 1023;
  float v[4][32];
  #pragma unroll
  for (int br = 0; br < 4; ++br) {
    const float* p = ze + (((size_t)br * BB + b) * TT + t) * EE;
    float s = 0.f;
    #pragma unroll
    for (int e = 0; e < 32; ++e) { v[br][e] = p[e]; s += v[br][e]*v[br][e]; }
    float nr = sqrtf(fmaxf(s, 1e-15f));
    float sc = tanhf(nr) / nr;
    float s2 = 0.f;
    #pragma unroll
    for (int e = 0; e < 32; ++e) { v[br][e] *= sc; s2 += v[br][e]*v[br][e]; }
    float n2 = sqrtf(fmaxf(s2, 1e-15f));
    if (n2 > 0.996f) {
      float sc2 = 0.996f / n2;
      #pragma unroll
      for (int e = 0; e < 32; ++e) v[br][e] *= sc2;
    }
    float* o = out + (((size_t)br * BB + b) * TT + t) * EE;
    #pragma unroll
    for (int e = 0; e < 32; ++e) o[e] = v[br][e];
  }
  float m1[32], m2[32];
  mobius_add32(v[1], v[2], m1);
  mobius_add32(v[0], m1, m2);
  mobius_add32(m2, v[3], m1);
  float s = 0.f;
  #pragma unroll
  for (int e = 0; e < 32; ++e) s += m1[e]*m1[e];
  float n = sqrtf(fmaxf(s, 1e-15f));
  if (n > 0.996f) {
    float sc = 0.996f / n;
    #pragma unroll
    for (int e = 0; e < 32; ++e) m1[e] *= sc;
  }
  float* o = out + (((size_t)4 * BB + b) * TT + t) * EE;
  #pragma unroll
  for (int e = 0; e < 32; ++e) o[e] = m1[e];
}

// ---------------- host ----------------
extern "C" void kernel_launch(void* const* d_in, const int* in_sizes, int n_in,
                              void* d_out, int out_size, void* d_ws, size_t ws_size,
                              hipStream_t stream) {
  const float* xs0 = (const float*)d_in[0];
  const float* xs1 = (const float*)d_in[1];
  const float* xs2 = (const float*)d_in[2];
  const float* xs3 = (const float*)d_in[3];
  const float* inpW   = (const float*)d_in[4];
  const float* inpb   = (const float*)d_in[5];
  const float* iprojW = (const float*)d_in[6];
  const float* convW  = (const float*)d_in[7];
  const float* convb  = (const float*)d_in[8];
  const float* xprojW = (const float*)d_in[9];
  const float* dtW    = (const float*)d_in[10];
  const float* dtb    = (const float*)d_in[11];
  const float* A_log  = (const float*)d_in[12];
  const float* D_skip = (const float*)d_in[13];
  const float* outW   = (const float*)d_in[14];
  const float* outpW  = (const float*)d_in[15];
  const float* outpb  = (const float*)d_in[16];
  float* out = (float*)d_out;
  float* ws  = (float*)d_ws;

  const size_t zeF = (size_t)4 * BB * TT * EE;
  // per fused batch row: h 65536 + xr/zb/u/dt 4*131072 + Bm/Cm 2*16384 + sdt 2048
  const size_t perBl = 65536 + 4 * 131072 + 2 * 16384 + 2048;
  auto needBytes = [&](int NB) { return (zeF + (size_t)NB * 32 * perBl) * 4; };
  int NB = 4;
  if (needBytes(4) > ws_size) NB = 2;
  if (NB == 2 && needBytes(2) > ws_size) NB = 1;
  const int nbl = NB * 32;

  float* ze = ws;
  float* h  = ze + zeF;
  float* xr = h  + (size_t)nbl * 65536;
  float* zb = xr + (size_t)nbl * 131072;
  float* u  = zb + (size_t)nbl * 131072;
  float* dt = u  + (size_t)nbl * 131072;
  float* Bm = dt + (size_t)nbl * 131072;
  float* Cm = Bm + (size_t)nbl * 16384;
  float* sdt = Cm + (size_t)nbl * 16384;
  float* g  = xr;   // alias: xr dead after k_xdbl, reused as y buffer
  float* Hloc = h;  // alias: h dead between k_xz (reads) and k_out (writes)

  for (int br0 = 0; br0 < 4; br0 += NB) {
    for (int l = 0; l < LL; ++l) {
      k_xz   <<<dim3(16, nbl), 256, 0, stream>>>(xs0, xs1, xs2, xs3, h, iprojW,
                                                 inpW, inpb, xr, zb, br0, l);
      k_xdbl <<<dim3(16, nbl), 256, 0, stream>>>(xr, convW, convb, xprojW, dtW, dtb,
                                                 u, dt, Bm, Cm, br0, l);
      k_scan1<<<nbl * 32, 256, 0, stream>>>(dt, u, Bm, Cm, A_log, D_skip,
                                            Hloc, g, sdt, br0, l);
      k_scan2<<<nbl * 64, 256, 0, stream>>>(dt, Cm, A_log, Hloc, sdt, g, br0, l);
      k_out  <<<dim3(16, nbl), 256, 0, stream>>>(g, zb, outW, h, br0, l);
    }
    k_ze<<<dim3(8, nbl), 256, 0, stream>>>(h, outpW, outpb, ze, br0);
  }
  k_hyper<<<BB * TT / 256, 256, 0, stream>>>(ze, out);
}

// Round 13
// 1051.062 us; speedup vs baseline: 1.2000x; 1.2000x over previous
//
#include <hip/hip_runtime.h>
#include <math.h>

#define TT 1024
#define DIN 128
#define HH 64
#define NN 16
#define EE 32
#define LL 3
#define BB 32

__device__ __forceinline__ float siluf(float x) { return x / (1.f + __expf(-x)); }

typedef __attribute__((ext_vector_type(8))) short bf16x8;
typedef __attribute__((ext_vector_type(4))) float f32x4;

// split fp32 into bf16 hi + bf16 lo (truncation; a ~= hi + lo, err ~2^-16 rel)
__device__ __forceinline__ void split2(float x, ushort& hi, ushort& lo) {
  unsigned u = __float_as_uint(x);
  hi = (ushort)(u >> 16);
  float rem = x - __uint_as_float((u >> 16) << 16);
  lo = (ushort)(__float_as_uint(rem) >> 16);
}

// ---------------- K1: xz = h @ inW^T via split-bf16 MFMA ----------------
// A-tile (h) staged+split ONCE per block; loops over the 4 n-tiles of W.
// l==0: A-tile computed on the fly from x*inpW+inpb (k_init folded in).
__global__ __launch_bounds__(256) void k_xz(
    const float* __restrict__ x0, const float* __restrict__ x1,
    const float* __restrict__ x2, const float* __restrict__ x3,
    const float* __restrict__ h, const float* __restrict__ inprojW,
    const float* __restrict__ inpW, const float* __restrict__ inpb,
    float* __restrict__ xr, float* __restrict__ zb, int br0, int l) {
  __shared__ __align__(16) ushort Hh[64][72], Hl[64][72];  // h tile [t][k]
  __shared__ __align__(16) ushort Wh[64][72], Wl[64][72];  // W tile [n][k]
  const int tid = threadIdx.x;
  const int b  = blockIdx.y;
  const int t0 = blockIdx.x * 64;
  const int br = br0 + (b >> 5);
  const float* Hg = h + ((size_t)b * TT + t0) * HH;
  const int row = tid >> 2, c0 = (tid & 3) * 16;
  {
    float xv = 0.f;
    if (l == 0) {
      int bb = b & 31;
      const float* xp = (br == 0) ? x0 : (br == 1) ? x1 : (br == 2) ? x2 : x3;
      xv = xp[bb * TT + t0 + row];
    }
    #pragma unroll
    for (int q = 0; q < 4; ++q) {
      float4 hv;
      if (l == 0) {
        float4 w4 = *(const float4*)(inpW + br * HH + c0 + q * 4);
        float4 b4 = *(const float4*)(inpb + br * HH + c0 + q * 4);
        hv.x = xv * w4.x + b4.x; hv.y = xv * w4.y + b4.y;
        hv.z = xv * w4.z + b4.z; hv.w = xv * w4.w + b4.w;
      } else {
        hv = *(const float4*)(Hg + (size_t)row * HH + c0 + q * 4);
      }
      ushort h0,h1,h2,h3,l0,l1,l2,l3;
      split2(hv.x,h0,l0); split2(hv.y,h1,l1); split2(hv.z,h2,l2); split2(hv.w,h3,l3);
      *(ushort4*)&Hh[row][c0 + q*4] = make_ushort4(h0,h1,h2,h3);
      *(ushort4*)&Hl[row][c0 + q*4] = make_ushort4(l0,l1,l2,l3);
    }
  }
  const int wave = tid >> 6, lane = tid & 63;
  const int quad = lane >> 4, l16 = lane & 15;
  const int nsub = (wave & 1) * 32, tsub = (wave >> 1) * 32;
  for (int n0 = 0; n0 < 2 * DIN; n0 += 64) {
    const float* Wg = inprojW + (size_t)((br * LL + l) * 2 * DIN + n0) * HH;
    {
      #pragma unroll
      for (int q = 0; q < 4; ++q) {
        float4 wv = *(const float4*)(Wg + (size_t)row * HH + c0 + q * 4);
        ushort h0,h1,h2,h3,l0,l1,l2,l3;
        split2(wv.x,h0,l0); split2(wv.y,h1,l1); split2(wv.z,h2,l2); split2(wv.w,h3,l3);
        *(ushort4*)&Wh[row][c0 + q*4] = make_ushort4(h0,h1,h2,h3);
        *(ushort4*)&Wl[row][c0 + q*4] = make_ushort4(l0,l1,l2,l3);
      }
    }
    __syncthreads();
    f32x4 acc[2][2] = {};   // [n-frag][t-frag]
    #pragma unroll
    for (int k0 = 0; k0 < 64; k0 += 32) {
      bf16x8 Ah[2], Al[2], Bh[2], Bl[2];
      #pragma unroll
      for (int i = 0; i < 2; ++i) {
        Ah[i] = *(const bf16x8*)&Wh[nsub + i*16 + l16][k0 + quad*8];
        Al[i] = *(const bf16x8*)&Wl[nsub + i*16 + l16][k0 + quad*8];
        Bh[i] = *(const bf16x8*)&Hh[tsub + i*16 + l16][k0 + quad*8];
        Bl[i] = *(const bf16x8*)&Hl[tsub + i*16 + l16][k0 + quad*8];
      }
      #pragma unroll
      for (int i = 0; i < 2; ++i)
        #pragma unroll
        for (int j = 0; j < 2; ++j) {
          acc[i][j] = __builtin_amdgcn_mfma_f32_16x16x32_bf16(Ah[i], Bh[j], acc[i][j], 0, 0, 0);
          acc[i][j] = __builtin_amdgcn_mfma_f32_16x16x32_bf16(Ah[i], Bl[j], acc[i][j], 0, 0, 0);
          acc[i][j] = __builtin_amdgcn_mfma_f32_16x16x32_bf16(Al[i], Bh[j], acc[i][j], 0, 0, 0);
        }
    }
    // D layout: col(t) = lane&15, row(n) = quad*4 + reg
    #pragma unroll
    for (int i = 0; i < 2; ++i) {
      #pragma unroll
      for (int r = 0; r < 4; ++r) {
        int n = n0 + nsub + i*16 + quad*4 + r;
        float* dst = (n < DIN) ? (xr + ((size_t)b * DIN + n) * TT)
                               : (zb + ((size_t)b * DIN + (n - DIN)) * TT);
        #pragma unroll
        for (int j = 0; j < 2; ++j)
          dst[t0 + tsub + j*16 + l16] = acc[i][j][r];
      }
    }
    __syncthreads();  // protect Wh/Wl before next n-tile restages
  }
}

// ---- K3: fused conv+silu into x_dbl GEMM (split-bf16 MFMA); writes u; dt epilogue ----
// W pre-split once per k0 into bf16 LDS; As2 padded to 70 (2-way banks = free).
__global__ __launch_bounds__(256) void k_xdbl(
    const float* __restrict__ xr, const float* __restrict__ convW,
    const float* __restrict__ convb, const float* __restrict__ xprojW,
    const float* __restrict__ dtW, const float* __restrict__ dtb,
    float* __restrict__ u, float* __restrict__ dt,
    float* __restrict__ Bm, float* __restrict__ Cm,
    int br0, int l) {
  __shared__ __align__(16) float Xr[16][72];
  __shared__ __align__(16) float As2[32][70];      // u tile, fp32 [k][t]
  __shared__ __align__(16) ushort Wh2[48][40], Wl2[48][40];  // W bf16 [n][k]
  __shared__ __align__(16) float Xs[40][68];
  const int tid = threadIdx.x;
  const int b  = blockIdx.y;
  const int t0 = blockIdx.x * 64;
  const int br = br0 + (b >> 5);
  const float* W = xprojW + (size_t)((br * LL + l) * 36) * DIN;
  const int rowk = tid >> 4, c4 = tid & 15;
  const int wave = tid >> 6, lane = tid & 63;
  const int quad = lane >> 4, l16 = lane & 15;
  const int tw = wave * 16;            // wave's t-offset
  f32x4 acc[3] = {};                   // 3 n-frags (n = 0..47), t = tw..tw+15
  for (int k0 = 0; k0 < DIN; k0 += 32) {
    #pragma unroll
    for (int ks = 0; ks < 32; ks += 16) {
      __syncthreads();
      {
        const float* src = xr + ((size_t)b * DIN + k0 + ks + rowk) * TT + t0;
        *(float4*)&Xr[rowk][4 + c4 * 4] = *(const float4*)(src + c4 * 4);
        if (tid < 16) {
          float4 hv = make_float4(0.f, 0.f, 0.f, 0.f);
          if (t0 > 0) hv = *(const float4*)(xr + ((size_t)b * DIN + k0 + ks + tid) * TT + t0 - 4);
          *(float4*)&Xr[tid][0] = hv;
        }
      }
      __syncthreads();
      {
        int d = k0 + ks + rowk;
        const float* w = convW + (size_t)((br * LL + l) * DIN + d) * 4;
        float w0 = w[0], w1 = w[1], w2 = w[2], w3 = w[3];
        float cb = convb[(br * LL + l) * DIN + d];
        int i0 = c4 * 4;
        float o[4];
        #pragma unroll
        for (int q = 0; q < 4; ++q) {
          int j = i0 + q;
          float a = Xr[rowk][j+1]*w0 + Xr[rowk][j+2]*w1 + Xr[rowk][j+3]*w2 + Xr[rowk][j+4]*w3 + cb;
          o[q] = siluf(a);
        }
        *(float2*)&As2[ks + rowk][i0]     = make_float2(o[0], o[1]);
        *(float2*)&As2[ks + rowk][i0 + 2] = make_float2(o[2], o[3]);
        *(float4*)(u + ((size_t)b * DIN + d) * TT + t0 + i0) =
            make_float4(o[0], o[1], o[2], o[3]);
      }
    }
    // stage + pre-split W chunk [48 n][32 k] (n >= 36 zeroed)
    for (int idx = tid; idx < 1536; idx += 256) {
      int jj = idx >> 5, kk = idx & 31;
      float v = (jj < 36) ? W[(size_t)jj * DIN + k0 + kk] : 0.f;
      ushort hi, lo; split2(v, hi, lo);
      Wh2[jj][kk] = hi; Wl2[jj][kk] = lo;
    }
    __syncthreads();
    // MFMA: A = W (rows n, bf16 pre-split), B = u (split in-register)
    ushort bh[8], bl[8];
    #pragma unroll
    for (int j = 0; j < 8; ++j) {
      float v = As2[quad * 8 + j][tw + l16];
      split2(v, bh[j], bl[j]);
    }
    bf16x8 Bh = *(bf16x8*)bh, Bl = *(bf16x8*)bl;
    #pragma unroll
    for (int nf = 0; nf < 3; ++nf) {
      bf16x8 Whf = *(const bf16x8*)&Wh2[nf * 16 + l16][quad * 8];
      bf16x8 Wlf = *(const bf16x8*)&Wl2[nf * 16 + l16][quad * 8];
      acc[nf] = __builtin_amdgcn_mfma_f32_16x16x32_bf16(Whf, Bh, acc[nf], 0, 0, 0);
      acc[nf] = __builtin_amdgcn_mfma_f32_16x16x32_bf16(Whf, Bl, acc[nf], 0, 0, 0);
      acc[nf] = __builtin_amdgcn_mfma_f32_16x16x32_bf16(Wlf, Bh, acc[nf], 0, 0, 0);
    }
  }
  __syncthreads();
  // D layout: col(t) = l16, row(n) = quad*4 + r  ->  Xs[n][t]
  #pragma unroll
  for (int nf = 0; nf < 3; ++nf) {
    #pragma unroll
    for (int r = 0; r < 4; ++r) {
      int n = nf * 16 + quad * 4 + r;
      if (n < 40) Xs[n][tw + l16] = acc[nf][r];
    }
  }
  __syncthreads();
  {
    int n = tid >> 4, i0 = (tid & 15) * 4;
    *(float4*)(Bm + ((size_t)b * NN + n) * TT + t0 + i0) = *(float4*)&Xs[4 + n][i0];
    *(float4*)(Cm + ((size_t)b * NN + n) * TT + t0 + i0) = *(float4*)&Xs[20 + n][i0];
  }
  {
    int d = tid >> 1, half = tid & 1;
    const float* wd = dtW + (size_t)((br * LL + l) * DIN + d) * 4;
    float w0 = wd[0], w1 = wd[1], w2 = wd[2], w3 = wd[3];
    float bias = dtb[(br * LL + l) * DIN + d];
    float* dtp = dt + ((size_t)b * DIN + d) * TT + t0 + half * 32;
    #pragma unroll
    for (int g8 = 0; g8 < 8; ++g8) {
      float o[4];
      #pragma unroll
      for (int q = 0; q < 4; ++q) {
        int i = half * 32 + g8 * 4 + q;
        float s = Xs[0][i]*w0 + Xs[1][i]*w1 + Xs[2][i]*w2 + Xs[3][i]*w3 + bias;
        float e = __expf(-fabsf(s));
        o[q] = fmaxf(s, 0.f) + __logf(1.f + e);
      }
      *(float4*)(dtp + g8*4) = make_float4(o[0], o[1], o[2], o[3]);
    }
  }
}

// ---- K4a: local chunk scan (chunk=64). Emits y_intra (g), Hloc, sdt (chunk dt-sums). ----
__global__ __launch_bounds__(256) void k_scan1(
    const float* __restrict__ dtc, const float* __restrict__ u,
    const float* __restrict__ Bm, const float* __restrict__ Cm,
    const float* __restrict__ A_log, const float* __restrict__ D_skip,
    float* __restrict__ Hloc, float* __restrict__ g, float* __restrict__ sdt,
    int br0, int l) {
  __shared__ __align__(16) float Bl[16][68];
  __shared__ __align__(16) float Cl[16][68];
  const int bx  = blockIdx.x;
  const int b   = bx >> 5;
  const int rem = bx & 31;
  const int c   = rem >> 1;
  const int dh  = rem & 1;
  const int tid = threadIdx.x;
  {
    int row = tid >> 4, cc = (tid & 15) * 4;
    *(float4*)&Bl[row][cc] = *(const float4*)(Bm + ((size_t)b * NN + row) * TT + c * 64 + cc);
    *(float4*)&Cl[row][cc] = *(const float4*)(Cm + ((size_t)b * NN + row) * TT + c * 64 + cc);
  }
  __syncthreads();
  const int d  = dh * 64 + (tid >> 2);
  const int n0 = (tid & 3) * 4;
  const int br = br0 + (b >> 5);
  const int wbase = (br * LL + l) * DIN + d;
  float Ac[4];
  #pragma unroll
  for (int j = 0; j < 4; ++j) Ac[j] = -__expf(A_log[(size_t)wbase * NN + n0 + j]);
  float Dp = D_skip[wbase];
  const float* dtp = dtc + ((size_t)b * DIN + d) * TT + c * 64;
  const float* up = u + ((size_t)b * DIN + d) * TT + c * 64;
  float* gp = g + ((size_t)b * DIN + d) * TT + c * 64;
  float hst[4] = {0.f, 0.f, 0.f, 0.f};
  float sd = 0.f;
  for (int t0 = 0; t0 < 64; t0 += 8) {
    float4 dq0 = *(const float4*)(dtp + t0);
    float4 dq1 = *(const float4*)(dtp + t0 + 4);
    float4 uq0 = *(const float4*)(up + t0);
    float4 uq1 = *(const float4*)(up + t0 + 4);
    float dts[8] = {dq0.x, dq0.y, dq0.z, dq0.w, dq1.x, dq1.y, dq1.z, dq1.w};
    float us[8]  = {uq0.x, uq0.y, uq0.z, uq0.w, uq1.x, uq1.y, uq1.z, uq1.w};
    float Bs[4][8], Cr[4][8];
    #pragma unroll
    for (int j = 0; j < 4; ++j) {
      float4 b0 = *(const float4*)&Bl[n0 + j][t0];
      float4 b1 = *(const float4*)&Bl[n0 + j][t0 + 4];
      Bs[j][0]=b0.x; Bs[j][1]=b0.y; Bs[j][2]=b0.z; Bs[j][3]=b0.w;
      Bs[j][4]=b1.x; Bs[j][5]=b1.y; Bs[j][6]=b1.z; Bs[j][7]=b1.w;
      float4 c0 = *(const float4*)&Cl[n0 + j][t0];
      float4 c1 = *(const float4*)&Cl[n0 + j][t0 + 4];
      Cr[j][0]=c0.x; Cr[j][1]=c0.y; Cr[j][2]=c0.z; Cr[j][3]=c0.w;
      Cr[j][4]=c1.x; Cr[j][5]=c1.y; Cr[j][6]=c1.z; Cr[j][7]=c1.w;
    }
    float yo[8];
    #pragma unroll
    for (int s = 0; s < 8; ++s) {
      float dtv = dts[s], uv = us[s];
      sd += dtv;
      float du = dtv * uv;
      float acc = 0.f;
      #pragma unroll
      for (int j = 0; j < 4; ++j) {
        float dA = __expf(dtv * Ac[j]);
        hst[j] = dA * hst[j] + du * Bs[j][s];
        acc += hst[j] * Cr[j][s];
      }
      acc += __shfl_xor(acc, 1, 4);
      acc += __shfl_xor(acc, 2, 4);
      yo[s] = acc + Dp * uv;
    }
    if ((tid & 3) == 0) {
      *(float4*)(gp + t0)     = make_float4(yo[0], yo[1], yo[2], yo[3]);
      *(float4*)(gp + t0 + 4) = make_float4(yo[4], yo[5], yo[6], yo[7]);
    }
  }
  *(float4*)(Hloc + (((size_t)b * DIN + d) * 16 + c) * 16 + n0) =
      make_float4(hst[0], hst[1], hst[2], hst[3]);
  if ((tid & 3) == 0) sdt[((size_t)b * DIN + d) * 16 + c] = sd;
}

// ---- K4c: combine (from Hloc + sdt) + parallel correction.
// cd recomputed from dt via in-LDS prefix (same serial order as scan1).
__global__ __launch_bounds__(256) void k_scan2(
    const float* __restrict__ dtc, const float* __restrict__ Cm,
    const float* __restrict__ A_log, const float* __restrict__ Hloc,
    const float* __restrict__ sdt, float* __restrict__ g, int br0, int l) {
  __shared__ __align__(16) float Cl[16][68];
  __shared__ __align__(16) float Dl[32][68];
  __shared__ __align__(16) float HinL[32][16];
  const int bx  = blockIdx.x;
  const int b   = bx >> 6;
  const int rem = bx & 63;
  const int c   = rem >> 2;
  const int dq  = rem & 3;
  const int tid = threadIdx.x;
  const int br  = br0 + (b >> 5);
  if (c == 0) return;  // h_in = 0 -> correction adds nothing
  {
    int row = tid >> 4, cc = (tid & 15) * 4;
    *(float4*)&Cl[row][cc] = *(const float4*)(Cm + ((size_t)b * NN + row) * TT + c * 64 + cc);
  }
  const int dloc = tid >> 3, tg = tid & 7;
  const int d  = dq * 32 + dloc;
  // stage this block's dt chunk [32 d][64 t]
  {
    const float* dp = dtc + ((size_t)b * DIN + d) * TT + c * 64 + tg * 8;
    *(float4*)&Dl[dloc][tg * 8]     = *(const float4*)dp;
    *(float4*)&Dl[dloc][tg * 8 + 4] = *(const float4*)(dp + 4);
  }
  // combine phase: h_in for this chunk, threads = (dloc 32) x (n-pair 8)
  {
    int n0 = (tid & 7) * 2;
    int wbase = (br * LL + l) * DIN + d;
    float a0 = -__expf(A_log[(size_t)wbase * NN + n0]);
    float a1 = -__expf(A_log[(size_t)wbase * NN + n0 + 1]);
    float h0 = 0.f, h1 = 0.f;
    const float* sp  = sdt + ((size_t)b * DIN + d) * 16;
    const float* hlb = Hloc + ((size_t)b * DIN + d) * 256;
    for (int cc = 0; cc < c; ++cc) {
      float sdv = sp[cc];
      float2 hl = *(const float2*)(hlb + cc * 16 + n0);
      h0 = __expf(a0 * sdv) * h0 + hl.x;
      h1 = __expf(a1 * sdv) * h1 + hl.y;
    }
    HinL[dloc][n0] = h0;
    HinL[dloc][n0 + 1] = h1;
  }
  __syncthreads();
  // recompute cd for this thread's 8 t's (serial ascending, same order as scan1)
  float cd8[8];
  {
    float run = 0.f;
    for (int t = 0; t < tg * 8; ++t) run += Dl[dloc][t];
    #pragma unroll
    for (int s = 0; s < 8; ++s) { run += Dl[dloc][tg * 8 + s]; cd8[s] = run; }
  }
  const float* al = A_log + (size_t)((br * LL + l) * DIN + d) * NN;
  float Ac16[16];
  #pragma unroll
  for (int n = 0; n < 16; ++n) Ac16[n] = -__expf(al[n]);
  size_t off = ((size_t)b * DIN + d) * TT + c * 64 + tg * 8;
  float* gp = g + off;
  float4 y0 = *(float4*)gp;
  float4 y1 = *(float4*)(gp + 4);
  float y8[8] = {y0.x, y0.y, y0.z, y0.w, y1.x, y1.y, y1.z, y1.w};
  const int tbase = tg * 8;
  #pragma unroll
  for (int n = 0; n < 16; ++n) {
    float hv = HinL[dloc][n];
    float an = Ac16[n];
    #pragma unroll
    for (int s = 0; s < 8; ++s)
      y8[s] += Cl[n][tbase + s] * __expf(an * cd8[s]) * hv;
  }
  *(float4*)gp       = make_float4(y8[0], y8[1], y8[2], y8[3]);
  *(float4*)(gp + 4) = make_float4(y8[4], y8[5], y8[6], y8[7]);
}

// ---------------- K5: h = (y * silu(z)) @ outW^T via split-bf16 MFMA ----------------
__global__ __launch_bounds__(256) void k_out(
    const float* __restrict__ graw, const float* __restrict__ zb,
    const float* __restrict__ outW, float* __restrict__ h, int br0, int l) {
  __shared__ __align__(16) ushort Ah_[64][72], Al_[64][72];  // outW tile [hh][k]
  __shared__ __align__(16) ushort Bh_[64][72], Bl_[64][72];  // act tile [d][t]
  const int tid = threadIdx.x;
  const int b  = blockIdx.y;
  const int t0 = blockIdx.x * 64;
  const int br = br0 + (b >> 5);
  const float* Wg = outW + (size_t)((br * LL + l) * HH) * DIN;
  const int wave = tid >> 6, lane = tid & 63;
  const int quad = lane >> 4, l16 = lane & 15;
  const int hsub = (wave & 1) * 32, tsub = (wave >> 1) * 32;
  f32x4 acc[2][2] = {};   // [hh-frag][t-frag]
  for (int k0 = 0; k0 < DIN; k0 += 64) {
    __syncthreads();
    {
      int row = tid >> 2, c0 = (tid & 3) * 16;
      #pragma unroll
      for (int q = 0; q < 4; ++q) {
        float4 wv = *(const float4*)(Wg + (size_t)row * DIN + k0 + c0 + q * 4);
        ushort h0,h1,h2,h3,l0,l1,l2,l3;
        split2(wv.x,h0,l0); split2(wv.y,h1,l1); split2(wv.z,h2,l2); split2(wv.w,h3,l3);
        *(ushort4*)&Ah_[row][c0 + q*4] = make_ushort4(h0,h1,h2,h3);
        *(ushort4*)&Al_[row][c0 + q*4] = make_ushort4(l0,l1,l2,l3);
        size_t off = ((size_t)b * DIN + k0 + row) * TT + t0 + c0 + q * 4;
        float4 gv = *(const float4*)(graw + off);
        float4 zv = *(const float4*)(zb + off);
        float a0 = gv.x * siluf(zv.x), a1 = gv.y * siluf(zv.y);
        float a2 = gv.z * siluf(zv.z), a3 = gv.w * siluf(zv.w);
        split2(a0,h0,l0); split2(a1,h1,l1); split2(a2,h2,l2); split2(a3,h3,l3);
        *(ushort4*)&Bh_[row][c0 + q*4] = make_ushort4(h0,h1,h2,h3);
        *(ushort4*)&Bl_[row][c0 + q*4] = make_ushort4(l0,l1,l2,l3);
      }
    }
    __syncthreads();
    #pragma unroll
    for (int kk = 0; kk < 64; kk += 32) {
      bf16x8 Ahf[2], Alf[2], Bhf[2], Blf[2];
      #pragma unroll
      for (int i = 0; i < 2; ++i) {
        Ahf[i] = *(const bf16x8*)&Ah_[hsub + i*16 + l16][kk + quad*8];
        Alf[i] = *(const bf16x8*)&Al_[hsub + i*16 + l16][kk + quad*8];
        Bhf[i] = *(const bf16x8*)&Bh_[tsub + i*16 + l16][kk + quad*8];
        Blf[i] = *(const bf16x8*)&Bl_[tsub + i*16 + l16][kk + quad*8];
      }
      #pragma unroll
      for (int i = 0; i < 2; ++i)
        #pragma unroll
        for (int j = 0; j < 2; ++j) {
          acc[i][j] = __builtin_amdgcn_mfma_f32_16x16x32_bf16(Ahf[i], Bhf[j], acc[i][j], 0, 0, 0);
          acc[i][j] = __builtin_amdgcn_mfma_f32_16x16x32_bf16(Ahf[i], Blf[j], acc[i][j], 0, 0, 0);
          acc[i][j] = __builtin_amdgcn_mfma_f32_16x16x32_bf16(Alf[i], Bhf[j], acc[i][j], 0, 0, 0);
        }
    }
  }
  #pragma unroll
  for (int i = 0; i < 2; ++i) {
    int hh0 = hsub + i*16 + quad*4;
    #pragma unroll
    for (int j = 0; j < 2; ++j) {
      int t = t0 + tsub + j*16 + l16;
      *(f32x4*)(h + ((size_t)b * TT + t) * HH + hh0) = acc[i][j];
    }
  }
}

// ---------------- K6: ze = tanh(h @ outp_W^T + outp_b) ----------------
__global__ __launch_bounds__(256) void k_ze(
    const float* __restrict__ h, const float* __restrict__ outpW,
    const float* __restrict__ outpb, float* __restrict__ ze, int br0) {
  __shared__ __align__(16) float As[16][132];
  __shared__ __align__(16) float Ws[16][36];
  __shared__ __align__(16) float Cs[128][36];
  const int tid = threadIdx.x;
  const int b  = blockIdx.y;
  const int t0 = blockIdx.x * 128;
  const int br = br0 + (b >> 5);
  const float* W = outpW + (size_t)br * EE * HH;
  float acc[4][4] = {};
  const int ti = tid & 31, ni = tid >> 5;
  for (int k0 = 0; k0 < HH; k0 += 16) {
    __syncthreads();
    {
      int i = tid >> 1, kq = (tid & 1) * 8;
      const float* src = h + ((size_t)b * TT + t0 + i) * HH + k0 + kq;
      float4 a0 = *(const float4*)src;
      float4 a1 = *(const float4*)(src + 4);
      As[kq+0][i]=a0.x; As[kq+1][i]=a0.y; As[kq+2][i]=a0.z; As[kq+3][i]=a0.w;
      As[kq+4][i]=a1.x; As[kq+5][i]=a1.y; As[kq+6][i]=a1.z; As[kq+7][i]=a1.w;
    }
    for (int idx = tid; idx < 512; idx += 256) {
      int jj = idx >> 4, kk = idx & 15;
      Ws[kk][jj] = W[(size_t)jj * HH + k0 + kk];
    }
    __syncthreads();
    #pragma unroll
    for (int kk = 0; kk < 16; ++kk) {
      float4 a = *(const float4*)&As[kk][ti * 4];
      float4 w = *(const float4*)&Ws[kk][ni * 4];
      acc[0][0] += a.x*w.x; acc[0][1] += a.x*w.y; acc[0][2] += a.x*w.z; acc[0][3] += a.x*w.w;
      acc[1][0] += a.y*w.x; acc[1][1] += a.y*w.y; acc[1][2] += a.y*w.z; acc[1][3] += a.y*w.w;
      acc[2][0] += a.z*w.x; acc[2][1] += a.z*w.y; acc[2][2] += a.z*w.z; acc[2][3] += a.z*w.w;
      acc[3][0] += a.w*w.x; acc[3][1] += a.w*w.y; acc[3][2] += a.w*w.z; acc[3][3] += a.w*w.w;
    }
  }
  __syncthreads();
  float bj[4];
  #pragma unroll
  for (int c = 0; c < 4; ++c) bj[c] = outpb[br * EE + ni*4 + c];
  #pragma unroll
  for (int r = 0; r < 4; ++r)
    #pragma unroll
    for (int c = 0; c < 4; ++c)
      Cs[ti*4+r][ni*4+c] = tanhf(acc[r][c] + bj[c]);
  __syncthreads();
  int i = tid >> 1, j16 = (tid & 1) * 16;
  float* dst = ze + (((size_t)(br0 * 32 + b)) * TT + t0 + i) * EE + j16;
  #pragma unroll
  for (int q = 0; q < 4; ++q)
    *(float4*)(dst + q*4) = *(float4*)&Cs[i][j16 + q*4];
}

// ---------------- K7: hyperbolic combine ----------------
__device__ __forceinline__ void mobius_add32(const float* x, const float* y, float* o) {
  float x2 = 0.f, y2 = 0.f, xy = 0.f;
  #pragma unroll
  for (int i = 0; i < 32; ++i) { x2 += x[i]*x[i]; y2 += y[i]*y[i]; xy += x[i]*y[i]; }
  float ca  = 1.f + 2.f*xy + y2;
  float cb  = 1.f - x2;
  float den = 1.f + 2.f*xy + x2*y2;
  float inv = 1.f / fmaxf(den, 1e-15f);
  #pragma unroll
  for (int i = 0; i < 32; ++i) o[i] = (ca*x[i] + cb*y[i]) * inv;
}

__global__ __launch_bounds__(256) void k_hyper(const float* __restrict__ ze,
                                               float* __restrict__ out) {
  int idx = blockIdx.x * 256 + threadIdx.x;
  int b = idx >> 10, t = idx & 1023;
  float v[4][32];
  #pragma unroll
  for (int br = 0; br < 4; ++br) {
    const float* p = ze + (((size_t)br * BB + b) * TT + t) * EE;
    float s = 0.f;
    #pragma unroll
    for (int e = 0; e < 32; ++e) { v[br][e] = p[e]; s += v[br][e]*v[br][e]; }
    float nr = sqrtf(fmaxf(s, 1e-15f));
    float sc = tanhf(nr) / nr;
    float s2 = 0.f;
    #pragma unroll
    for (int e = 0; e < 32; ++e) { v[br][e] *= sc; s2 += v[br][e]*v[br][e]; }
    float n2 = sqrtf(fmaxf(s2, 1e-15f));
    if (n2 > 0.996f) {
      float sc2 = 0.996f / n2;
      #pragma unroll
      for (int e = 0; e < 32; ++e) v[br][e] *= sc2;
    }
    float* o = out + (((size_t)br * BB + b) * TT + t) * EE;
    #pragma unroll
    for (int e = 0; e < 32; ++e) o[e] = v[br][e];
  }
  float m1[32], m2[32];
  mobius_add32(v[1], v[2], m1);
  mobius_add32(v[0], m1, m2);
  mobius_add32(m2, v[3], m1);
  float s = 0.f;
  #pragma unroll
  for (int e = 0; e < 32; ++e) s += m1[e]*m1[e];
  float n = sqrtf(fmaxf(s, 1e-15f));
  if (n > 0.996f) {
    float sc = 0.996f / n;
    #pragma unroll
    for (int e = 0; e < 32; ++e) m1[e] *= sc;
  }
  float* o = out + (((size_t)4 * BB + b) * TT + t) * EE;
  #pragma unroll
  for (int e = 0; e < 32; ++e) o[e] = m1[e];
}

// ---------------- host ----------------
extern "C" void kernel_launch(void* const* d_in, const int* in_sizes, int n_in,
                              void* d_out, int out_size, void* d_ws, size_t ws_size,
                              hipStream_t stream) {
  const float* xs0 = (const float*)d_in[0];
  const float* xs1 = (const float*)d_in[1];
  const float* xs2 = (const float*)d_in[2];
  const float* xs3 = (const float*)d_in[3];
  const float* inpW   = (const float*)d_in[4];
  const float* inpb   = (const float*)d_in[5];
  const float* iprojW = (const float*)d_in[6];
  const float* convW  = (const float*)d_in[7];
  const float* convb  = (const float*)d_in[8];
  const float* xprojW = (const float*)d_in[9];
  const float* dtW    = (const float*)d_in[10];
  const float* dtb    = (const float*)d_in[11];
  const float* A_log  = (const float*)d_in[12];
  const float* D_skip = (const float*)d_in[13];
  const float* outW   = (const float*)d_in[14];
  const float* outpW  = (const float*)d_in[15];
  const float* outpb  = (const float*)d_in[16];
  float* out = (float*)d_out;
  float* ws  = (float*)d_ws;

  const size_t zeF = (size_t)4 * BB * TT * EE;
  // per fused batch row: h 65536 + xr/zb/u/dt 4*131072 + Bm/Cm 2*16384 + sdt 2048
  const size_t perBl = 65536 + 4 * 131072 + 2 * 16384 + 2048;
  auto needBytes = [&](int NB) { return (zeF + (size_t)NB * 32 * perBl) * 4; };
  int NB = 4;
  if (needBytes(4) > ws_size) NB = 2;
  if (NB == 2 && needBytes(2) > ws_size) NB = 1;
  const int nbl = NB * 32;

  float* ze = ws;
  float* h  = ze + zeF;
  float* xr = h  + (size_t)nbl * 65536;
  float* zb = xr + (size_t)nbl * 131072;
  float* u  = zb + (size_t)nbl * 131072;
  float* dt = u  + (size_t)nbl * 131072;
  float* Bm = dt + (size_t)nbl * 131072;
  float* Cm = Bm + (size_t)nbl * 16384;
  float* sdt = Cm + (size_t)nbl * 16384;
  float* g  = xr;   // alias: xr dead after k_xdbl, reused as y buffer
  float* Hloc = h;  // alias: h dead between k_xz (reads) and k_out (writes)

  for (int br0 = 0; br0 < 4; br0 += NB) {
    for (int l = 0; l < LL; ++l) {
      k_xz   <<<dim3(16, nbl), 256, 0, stream>>>(xs0, xs1, xs2, xs3, h, iprojW,
                                                 inpW, inpb, xr, zb, br0, l);
      k_xdbl <<<dim3(16, nbl), 256, 0, stream>>>(xr, convW, convb, xprojW, dtW, dtb,
                                                 u, dt, Bm, Cm, br0, l);
      k_scan1<<<nbl * 32, 256, 0, stream>>>(dt, u, Bm, Cm, A_log, D_skip,
                                            Hloc, g, sdt, br0, l);
      k_scan2<<<nbl * 64, 256, 0, stream>>>(dt, Cm, A_log, Hloc, sdt, g, br0, l);
      k_out  <<<dim3(16, nbl), 256, 0, stream>>>(g, zb, outW, h, br0, l);
    }
    k_ze<<<dim3(8, nbl), 256, 0, stream>>>(h, outpW, outpb, ze, br0);
  }
  k_hyper<<<BB * TT / 256, 256, 0, stream>>>(ze, out);
}

// Round 14
// 999.881 us; speedup vs baseline: 1.2614x; 1.0512x over previous
//
#include <hip/hip_runtime.h>
#include <math.h>

#define TT 1024
#define DIN 128
#define HH 64
#define NN 16
#define EE 32
#define LL 3
#define BB 32

__device__ __forceinline__ float siluf(float x) { return x / (1.f + __expf(-x)); }

typedef __attribute__((ext_vector_type(8))) short bf16x8;
typedef __attribute__((ext_vector_type(4))) float f32x4;

// split fp32 into bf16 hi + bf16 lo (truncation; a ~= hi + lo, err ~2^-16 rel)
__device__ __forceinline__ void split2(float x, ushort& hi, ushort& lo) {
  unsigned u = __float_as_uint(x);
  hi = (ushort)(u >> 16);
  float rem = x - __uint_as_float((u >> 16) << 16);
  lo = (ushort)(__float_as_uint(rem) >> 16);
}

// ---------------- K1: xz = h @ inW^T via split-bf16 MFMA ----------------
// A-tile (h) staged+split ONCE per block; loops over the 4 n-tiles of W.
// l==0: A-tile computed on the fly from x*inpW+inpb (k_init folded in).
__global__ __launch_bounds__(256) void k_xz(
    const float* __restrict__ x0, const float* __restrict__ x1,
    const float* __restrict__ x2, const float* __restrict__ x3,
    const float* __restrict__ h, const float* __restrict__ inprojW,
    const float* __restrict__ inpW, const float* __restrict__ inpb,
    float* __restrict__ xr, float* __restrict__ zb, int br0, int l) {
  __shared__ __align__(16) ushort Hh[64][72], Hl[64][72];  // h tile [t][k]
  __shared__ __align__(16) ushort Wh[64][72], Wl[64][72];  // W tile [n][k]
  const int tid = threadIdx.x;
  const int b  = blockIdx.y;
  const int t0 = blockIdx.x * 64;
  const int br = br0 + (b >> 5);
  const float* Hg = h + ((size_t)b * TT + t0) * HH;
  const int row = tid >> 2, c0 = (tid & 3) * 16;
  {
    float xv = 0.f;
    if (l == 0) {
      int bb = b & 31;
      const float* xp = (br == 0) ? x0 : (br == 1) ? x1 : (br == 2) ? x2 : x3;
      xv = xp[bb * TT + t0 + row];
    }
    #pragma unroll
    for (int q = 0; q < 4; ++q) {
      float4 hv;
      if (l == 0) {
        float4 w4 = *(const float4*)(inpW + br * HH + c0 + q * 4);
        float4 b4 = *(const float4*)(inpb + br * HH + c0 + q * 4);
        hv.x = xv * w4.x + b4.x; hv.y = xv * w4.y + b4.y;
        hv.z = xv * w4.z + b4.z; hv.w = xv * w4.w + b4.w;
      } else {
        hv = *(const float4*)(Hg + (size_t)row * HH + c0 + q * 4);
      }
      ushort h0,h1,h2,h3,l0,l1,l2,l3;
      split2(hv.x,h0,l0); split2(hv.y,h1,l1); split2(hv.z,h2,l2); split2(hv.w,h3,l3);
      *(ushort4*)&Hh[row][c0 + q*4] = make_ushort4(h0,h1,h2,h3);
      *(ushort4*)&Hl[row][c0 + q*4] = make_ushort4(l0,l1,l2,l3);
    }
  }
  const int wave = tid >> 6, lane = tid & 63;
  const int quad = lane >> 4, l16 = lane & 15;
  const int nsub = (wave & 1) * 32, tsub = (wave >> 1) * 32;
  for (int n0 = 0; n0 < 2 * DIN; n0 += 64) {
    const float* Wg = inprojW + (size_t)((br * LL + l) * 2 * DIN + n0) * HH;
    {
      #pragma unroll
      for (int q = 0; q < 4; ++q) {
        float4 wv = *(const float4*)(Wg + (size_t)row * HH + c0 + q * 4);
        ushort h0,h1,h2,h3,l0,l1,l2,l3;
        split2(wv.x,h0,l0); split2(wv.y,h1,l1); split2(wv.z,h2,l2); split2(wv.w,h3,l3);
        *(ushort4*)&Wh[row][c0 + q*4] = make_ushort4(h0,h1,h2,h3);
        *(ushort4*)&Wl[row][c0 + q*4] = make_ushort4(l0,l1,l2,l3);
      }
    }
    __syncthreads();
    f32x4 acc[2][2] = {};   // [n-frag][t-frag]
    #pragma unroll
    for (int k0 = 0; k0 < 64; k0 += 32) {
      bf16x8 Ah[2], Al[2], Bh[2], Bl[2];
      #pragma unroll
      for (int i = 0; i < 2; ++i) {
        Ah[i] = *(const bf16x8*)&Wh[nsub + i*16 + l16][k0 + quad*8];
        Al[i] = *(const bf16x8*)&Wl[nsub + i*16 + l16][k0 + quad*8];
        Bh[i] = *(const bf16x8*)&Hh[tsub + i*16 + l16][k0 + quad*8];
        Bl[i] = *(const bf16x8*)&Hl[tsub + i*16 + l16][k0 + quad*8];
      }
      #pragma unroll
      for (int i = 0; i < 2; ++i)
        #pragma unroll
        for (int j = 0; j < 2; ++j) {
          acc[i][j] = __builtin_amdgcn_mfma_f32_16x16x32_bf16(Ah[i], Bh[j], acc[i][j], 0, 0, 0);
          acc[i][j] = __builtin_amdgcn_mfma_f32_16x16x32_bf16(Ah[i], Bl[j], acc[i][j], 0, 0, 0);
          acc[i][j] = __builtin_amdgcn_mfma_f32_16x16x32_bf16(Al[i], Bh[j], acc[i][j], 0, 0, 0);
        }
    }
    // D layout: col(t) = lane&15, row(n) = quad*4 + reg
    #pragma unroll
    for (int i = 0; i < 2; ++i) {
      #pragma unroll
      for (int r = 0; r < 4; ++r) {
        int n = n0 + nsub + i*16 + quad*4 + r;
        float* dst = (n < DIN) ? (xr + ((size_t)b * DIN + n) * TT)
                               : (zb + ((size_t)b * DIN + (n - DIN)) * TT);
        #pragma unroll
        for (int j = 0; j < 2; ++j)
          dst[t0 + tsub + j*16 + l16] = acc[i][j][r];
      }
    }
    __syncthreads();  // protect Wh/Wl before next n-tile restages
  }
}

// ---- K3: fused conv+silu into x_dbl GEMM (split-bf16 MFMA); writes u; dt epilogue ----
// (R9/R10 measured-good version: fp32 W tile, in-register splits)
__global__ __launch_bounds__(256) void k_xdbl(
    const float* __restrict__ xr, const float* __restrict__ convW,
    const float* __restrict__ convb, const float* __restrict__ xprojW,
    const float* __restrict__ dtW, const float* __restrict__ dtb,
    float* __restrict__ u, float* __restrict__ dt,
    float* __restrict__ Bm, float* __restrict__ Cm,
    int br0, int l) {
  __shared__ __align__(16) float Xr[16][72];
  __shared__ __align__(16) float As2[32][68];  // u tile, fp32 [k][t]
  __shared__ __align__(16) float Ws2[32][48];  // W tile, fp32 [k][n], n>=36 zero
  __shared__ __align__(16) float Xs[40][68];
  const int tid = threadIdx.x;
  const int b  = blockIdx.y;
  const int t0 = blockIdx.x * 64;
  const int br = br0 + (b >> 5);
  const float* W = xprojW + (size_t)((br * LL + l) * 36) * DIN;
  const int rowk = tid >> 4, c4 = tid & 15;
  const int wave = tid >> 6, lane = tid & 63;
  const int quad = lane >> 4, l16 = lane & 15;
  const int tw = wave * 16;            // wave's t-offset
  f32x4 acc[3] = {};                   // 3 n-frags (n = 0..47), t = tw..tw+15
  for (int k0 = 0; k0 < DIN; k0 += 32) {
    #pragma unroll
    for (int ks = 0; ks < 32; ks += 16) {
      __syncthreads();
      {
        const float* src = xr + ((size_t)b * DIN + k0 + ks + rowk) * TT + t0;
        *(float4*)&Xr[rowk][4 + c4 * 4] = *(const float4*)(src + c4 * 4);
        if (tid < 16) {
          float4 hv = make_float4(0.f, 0.f, 0.f, 0.f);
          if (t0 > 0) hv = *(const float4*)(xr + ((size_t)b * DIN + k0 + ks + tid) * TT + t0 - 4);
          *(float4*)&Xr[tid][0] = hv;
        }
      }
      __syncthreads();
      {
        int d = k0 + ks + rowk;
        const float* w = convW + (size_t)((br * LL + l) * DIN + d) * 4;
        float w0 = w[0], w1 = w[1], w2 = w[2], w3 = w[3];
        float cb = convb[(br * LL + l) * DIN + d];
        int i0 = c4 * 4;
        float o[4];
        #pragma unroll
        for (int q = 0; q < 4; ++q) {
          int j = i0 + q;
          float a = Xr[rowk][j+1]*w0 + Xr[rowk][j+2]*w1 + Xr[rowk][j+3]*w2 + Xr[rowk][j+4]*w3 + cb;
          o[q] = siluf(a);
        }
        float4 uo = make_float4(o[0], o[1], o[2], o[3]);
        *(float4*)&As2[ks + rowk][i0] = uo;
        *(float4*)(u + ((size_t)b * DIN + d) * TT + t0 + i0) = uo;
      }
    }
    // stage W chunk [32 k][48 n] (n >= 36 zeroed)
    for (int idx = tid; idx < 1536; idx += 256) {
      int jj = idx >> 5, kk = idx & 31;
      Ws2[kk][jj] = (jj < 36) ? W[(size_t)jj * DIN + k0 + kk] : 0.f;
    }
    __syncthreads();
    // MFMA: A = W (rows n), B = u (rows t); k = quad*8 + 0..7
    ushort bh[8], bl[8];
    #pragma unroll
    for (int j = 0; j < 8; ++j) {
      float v = As2[quad * 8 + j][tw + l16];
      split2(v, bh[j], bl[j]);
    }
    bf16x8 Bh = *(bf16x8*)bh, Bl = *(bf16x8*)bl;
    #pragma unroll
    for (int nf = 0; nf < 3; ++nf) {
      ushort wh[8], wl[8];
      #pragma unroll
      for (int j = 0; j < 8; ++j) {
        float v = Ws2[quad * 8 + j][nf * 16 + l16];
        split2(v, wh[j], wl[j]);
      }
      bf16x8 Wh = *(bf16x8*)wh, Wl = *(bf16x8*)wl;
      acc[nf] = __builtin_amdgcn_mfma_f32_16x16x32_bf16(Wh, Bh, acc[nf], 0, 0, 0);
      acc[nf] = __builtin_amdgcn_mfma_f32_16x16x32_bf16(Wh, Bl, acc[nf], 0, 0, 0);
      acc[nf] = __builtin_amdgcn_mfma_f32_16x16x32_bf16(Wl, Bh, acc[nf], 0, 0, 0);
    }
  }
  __syncthreads();
  // D layout: col(t) = l16, row(n) = quad*4 + r  ->  Xs[n][t]
  #pragma unroll
  for (int nf = 0; nf < 3; ++nf) {
    #pragma unroll
    for (int r = 0; r < 4; ++r) {
      int n = nf * 16 + quad * 4 + r;
      if (n < 40) Xs[n][tw + l16] = acc[nf][r];
    }
  }
  __syncthreads();
  {
    int n = tid >> 4, i0 = (tid & 15) * 4;
    *(float4*)(Bm + ((size_t)b * NN + n) * TT + t0 + i0) = *(float4*)&Xs[4 + n][i0];
    *(float4*)(Cm + ((size_t)b * NN + n) * TT + t0 + i0) = *(float4*)&Xs[20 + n][i0];
  }
  {
    int d = tid >> 1, half = tid & 1;
    const float* wd = dtW + (size_t)((br * LL + l) * DIN + d) * 4;
    float w0 = wd[0], w1 = wd[1], w2 = wd[2], w3 = wd[3];
    float bias = dtb[(br * LL + l) * DIN + d];
    float* dtp = dt + ((size_t)b * DIN + d) * TT + t0 + half * 32;
    #pragma unroll
    for (int g8 = 0; g8 < 8; ++g8) {
      float o[4];
      #pragma unroll
      for (int q = 0; q < 4; ++q) {
        int i = half * 32 + g8 * 4 + q;
        float s = Xs[0][i]*w0 + Xs[1][i]*w1 + Xs[2][i]*w2 + Xs[3][i]*w3 + bias;
        float e = __expf(-fabsf(s));
        o[q] = fmaxf(s, 0.f) + __logf(1.f + e);
      }
      *(float4*)(dtp + g8*4) = make_float4(o[0], o[1], o[2], o[3]);
    }
  }
}

// ---- K4a: local chunk scan (chunk=64). Emits y_intra (g), Hloc, sdt (chunk dt-sums). ----
__global__ __launch_bounds__(256) void k_scan1(
    const float* __restrict__ dtc, const float* __restrict__ u,
    const float* __restrict__ Bm, const float* __restrict__ Cm,
    const float* __restrict__ A_log, const float* __restrict__ D_skip,
    float* __restrict__ Hloc, float* __restrict__ g, float* __restrict__ sdt,
    int br0, int l) {
  __shared__ __align__(16) float Bl[16][68];
  __shared__ __align__(16) float Cl[16][68];
  const int bx  = blockIdx.x;
  const int b   = bx >> 5;
  const int rem = bx & 31;
  const int c   = rem >> 1;
  const int dh  = rem & 1;
  const int tid = threadIdx.x;
  {
    int row = tid >> 4, cc = (tid & 15) * 4;
    *(float4*)&Bl[row][cc] = *(const float4*)(Bm + ((size_t)b * NN + row) * TT + c * 64 + cc);
    *(float4*)&Cl[row][cc] = *(const float4*)(Cm + ((size_t)b * NN + row) * TT + c * 64 + cc);
  }
  __syncthreads();
  const int d  = dh * 64 + (tid >> 2);
  const int n0 = (tid & 3) * 4;
  const int br = br0 + (b >> 5);
  const int wbase = (br * LL + l) * DIN + d;
  float Ac[4];
  #pragma unroll
  for (int j = 0; j < 4; ++j) Ac[j] = -__expf(A_log[(size_t)wbase * NN + n0 + j]);
  float Dp = D_skip[wbase];
  const float* dtp = dtc + ((size_t)b * DIN + d) * TT + c * 64;
  const float* up = u + ((size_t)b * DIN + d) * TT + c * 64;
  float* gp = g + ((size_t)b * DIN + d) * TT + c * 64;
  float hst[4] = {0.f, 0.f, 0.f, 0.f};
  float sd = 0.f;
  for (int t0 = 0; t0 < 64; t0 += 8) {
    float4 dq0 = *(const float4*)(dtp + t0);
    float4 dq1 = *(const float4*)(dtp + t0 + 4);
    float4 uq0 = *(const float4*)(up + t0);
    float4 uq1 = *(const float4*)(up + t0 + 4);
    float dts[8] = {dq0.x, dq0.y, dq0.z, dq0.w, dq1.x, dq1.y, dq1.z, dq1.w};
    float us[8]  = {uq0.x, uq0.y, uq0.z, uq0.w, uq1.x, uq1.y, uq1.z, uq1.w};
    float Bs[4][8], Cr[4][8];
    #pragma unroll
    for (int j = 0; j < 4; ++j) {
      float4 b0 = *(const float4*)&Bl[n0 + j][t0];
      float4 b1 = *(const float4*)&Bl[n0 + j][t0 + 4];
      Bs[j][0]=b0.x; Bs[j][1]=b0.y; Bs[j][2]=b0.z; Bs[j][3]=b0.w;
      Bs[j][4]=b1.x; Bs[j][5]=b1.y; Bs[j][6]=b1.z; Bs[j][7]=b1.w;
      float4 c0 = *(const float4*)&Cl[n0 + j][t0];
      float4 c1 = *(const float4*)&Cl[n0 + j][t0 + 4];
      Cr[j][0]=c0.x; Cr[j][1]=c0.y; Cr[j][2]=c0.z; Cr[j][3]=c0.w;
      Cr[j][4]=c1.x; Cr[j][5]=c1.y; Cr[j][6]=c1.z; Cr[j][7]=c1.w;
    }
    float yo[8];
    #pragma unroll
    for (int s = 0; s < 8; ++s) {
      float dtv = dts[s], uv = us[s];
      sd += dtv;
      float du = dtv * uv;
      float acc = 0.f;
      #pragma unroll
      for (int j = 0; j < 4; ++j) {
        float dA = __expf(dtv * Ac[j]);
        hst[j] = dA * hst[j] + du * Bs[j][s];
        acc += hst[j] * Cr[j][s];
      }
      acc += __shfl_xor(acc, 1, 4);
      acc += __shfl_xor(acc, 2, 4);
      yo[s] = acc + Dp * uv;
    }
    if ((tid & 3) == 0) {
      *(float4*)(gp + t0)     = make_float4(yo[0], yo[1], yo[2], yo[3]);
      *(float4*)(gp + t0 + 4) = make_float4(yo[4], yo[5], yo[6], yo[7]);
    }
  }
  *(float4*)(Hloc + (((size_t)b * DIN + d) * 16 + c) * 16 + n0) =
      make_float4(hst[0], hst[1], hst[2], hst[3]);
  if ((tid & 3) == 0) sdt[((size_t)b * DIN + d) * 16 + c] = sd;
}

// ---- K4c: combine (from Hloc + sdt) + parallel correction.
// Grid covers c in [1,15] only (c==0 needs no correction).
__global__ __launch_bounds__(256) void k_scan2(
    const float* __restrict__ dtc, const float* __restrict__ Cm,
    const float* __restrict__ A_log, const float* __restrict__ Hloc,
    const float* __restrict__ sdt, float* __restrict__ g, int br0, int l) {
  __shared__ __align__(16) float Cl[16][68];
  __shared__ __align__(16) float Dl[32][68];
  __shared__ __align__(16) float HinL[32][16];
  const int bx  = blockIdx.x;
  const int b   = bx / 60;
  const int rem = bx % 60;
  const int c   = (rem >> 2) + 1;   // 1..15
  const int dq  = rem & 3;
  const int tid = threadIdx.x;
  const int br  = br0 + (b >> 5);
  {
    int row = tid >> 4, cc = (tid & 15) * 4;
    *(float4*)&Cl[row][cc] = *(const float4*)(Cm + ((size_t)b * NN + row) * TT + c * 64 + cc);
  }
  const int dloc = tid >> 3, tg = tid & 7;
  const int d  = dq * 32 + dloc;
  // stage this block's dt chunk [32 d][64 t]
  {
    const float* dp = dtc + ((size_t)b * DIN + d) * TT + c * 64 + tg * 8;
    *(float4*)&Dl[dloc][tg * 8]     = *(const float4*)dp;
    *(float4*)&Dl[dloc][tg * 8 + 4] = *(const float4*)(dp + 4);
  }
  // combine phase: h_in for this chunk, threads = (dloc 32) x (n-pair 8)
  {
    int n0 = (tid & 7) * 2;
    int wbase = (br * LL + l) * DIN + d;
    float a0 = -__expf(A_log[(size_t)wbase * NN + n0]);
    float a1 = -__expf(A_log[(size_t)wbase * NN + n0 + 1]);
    float h0 = 0.f, h1 = 0.f;
    const float* sp  = sdt + ((size_t)b * DIN + d) * 16;
    const float* hlb = Hloc + ((size_t)b * DIN + d) * 256;
    for (int cc = 0; cc < c; ++cc) {
      float sdv = sp[cc];
      float2 hl = *(const float2*)(hlb + cc * 16 + n0);
      h0 = __expf(a0 * sdv) * h0 + hl.x;
      h1 = __expf(a1 * sdv) * h1 + hl.y;
    }
    HinL[dloc][n0] = h0;
    HinL[dloc][n0 + 1] = h1;
  }
  __syncthreads();
  // recompute cd for this thread's 8 t's (serial ascending, same order as scan1)
  float cd8[8];
  {
    float run = 0.f;
    for (int t = 0; t < tg * 8; ++t) run += Dl[dloc][t];
    #pragma unroll
    for (int s = 0; s < 8; ++s) { run += Dl[dloc][tg * 8 + s]; cd8[s] = run; }
  }
  const float* al = A_log + (size_t)((br * LL + l) * DIN + d) * NN;
  float Ac16[16];
  #pragma unroll
  for (int n = 0; n < 16; ++n) Ac16[n] = -__expf(al[n]);
  size_t off = ((size_t)b * DIN + d) * TT + c * 64 + tg * 8;
  float* gp = g + off;
  float4 y0 = *(float4*)gp;
  float4 y1 = *(float4*)(gp + 4);
  float y8[8] = {y0.x, y0.y, y0.z, y0.w, y1.x, y1.y, y1.z, y1.w};
  const int tbase = tg * 8;
  #pragma unroll
  for (int n = 0; n < 16; ++n) {
    float hv = HinL[dloc][n];
    float an = Ac16[n];
    #pragma unroll
    for (int s = 0; s < 8; ++s)
      y8[s] += Cl[n][tbase + s] * __expf(an * cd8[s]) * hv;
  }
  *(float4*)gp       = make_float4(y8[0], y8[1], y8[2], y8[3]);
  *(float4*)(gp + 4) = make_float4(y8[4], y8[5], y8[6], y8[7]);
}

// ---------------- K5: h = (y * silu(z)) @ outW^T via split-bf16 MFMA ----------------
__global__ __launch_bounds__(256) void k_out(
    const float* __restrict__ graw, const float* __restrict__ zb,
    const float* __restrict__ outW, float* __restrict__ h, int br0, int l) {
  __shared__ __align__(16) ushort Ah_[64][72], Al_[64][72];  // outW tile [hh][k]
  __shared__ __align__(16) ushort Bh_[64][72], Bl_[64][72];  // act tile [d][t]
  const int tid = threadIdx.x;
  const int b  = blockIdx.y;
  const int t0 = blockIdx.x * 64;
  const int br = br0 + (b >> 5);
  const float* Wg = outW + (size_t)((br * LL + l) * HH) * DIN;
  const int wave = tid >> 6, lane = tid & 63;
  const int quad = lane >> 4, l16 = lane & 15;
  const int hsub = (wave & 1) * 32, tsub = (wave >> 1) * 32;
  f32x4 acc[2][2] = {};   // [hh-frag][t-frag]
  for (int k0 = 0; k0 < DIN; k0 += 64) {
    __syncthreads();
    {
      int row = tid >> 2, c0 = (tid & 3) * 16;
      #pragma unroll
      for (int q = 0; q < 4; ++q) {
        float4 wv = *(const float4*)(Wg + (size_t)row * DIN + k0 + c0 + q * 4);
        ushort h0,h1,h2,h3,l0,l1,l2,l3;
        split2(wv.x,h0,l0); split2(wv.y,h1,l1); split2(wv.z,h2,l2); split2(wv.w,h3,l3);
        *(ushort4*)&Ah_[row][c0 + q*4] = make_ushort4(h0,h1,h2,h3);
        *(ushort4*)&Al_[row][c0 + q*4] = make_ushort4(l0,l1,l2,l3);
        size_t off = ((size_t)b * DIN + k0 + row) * TT + t0 + c0 + q * 4;
        float4 gv = *(const float4*)(graw + off);
        float4 zv = *(const float4*)(zb + off);
        float a0 = gv.x * siluf(zv.x), a1 = gv.y * siluf(zv.y);
        float a2 = gv.z * siluf(zv.z), a3 = gv.w * siluf(zv.w);
        split2(a0,h0,l0); split2(a1,h1,l1); split2(a2,h2,l2); split2(a3,h3,l3);
        *(ushort4*)&Bh_[row][c0 + q*4] = make_ushort4(h0,h1,h2,h3);
        *(ushort4*)&Bl_[row][c0 + q*4] = make_ushort4(l0,l1,l2,l3);
      }
    }
    __syncthreads();
    #pragma unroll
    for (int kk = 0; kk < 64; kk += 32) {
      bf16x8 Ahf[2], Alf[2], Bhf[2], Blf[2];
      #pragma unroll
      for (int i = 0; i < 2; ++i) {
        Ahf[i] = *(const bf16x8*)&Ah_[hsub + i*16 + l16][kk + quad*8];
        Alf[i] = *(const bf16x8*)&Al_[hsub + i*16 + l16][kk + quad*8];
        Bhf[i] = *(const bf16x8*)&Bh_[tsub + i*16 + l16][kk + quad*8];
        Blf[i] = *(const bf16x8*)&Bl_[tsub + i*16 + l16][kk + quad*8];
      }
      #pragma unroll
      for (int i = 0; i < 2; ++i)
        #pragma unroll
        for (int j = 0; j < 2; ++j) {
          acc[i][j] = __builtin_amdgcn_mfma_f32_16x16x32_bf16(Ahf[i], Bhf[j], acc[i][j], 0, 0, 0);
          acc[i][j] = __builtin_amdgcn_mfma_f32_16x16x32_bf16(Ahf[i], Blf[j], acc[i][j], 0, 0, 0);
          acc[i][j] = __builtin_amdgcn_mfma_f32_16x16x32_bf16(Alf[i], Bhf[j], acc[i][j], 0, 0, 0);
        }
    }
  }
  #pragma unroll
  for (int i = 0; i < 2; ++i) {
    int hh0 = hsub + i*16 + quad*4;
    #pragma unroll
    for (int j = 0; j < 2; ++j) {
      int t = t0 + tsub + j*16 + l16;
      *(f32x4*)(h + ((size_t)b * TT + t) * HH + hh0) = acc[i][j];
    }
  }
}

// ---------------- K6: ze = tanh(h @ outp_W^T + outp_b) ----------------
__global__ __launch_bounds__(256) void k_ze(
    const float* __restrict__ h, const float* __restrict__ outpW,
    const float* __restrict__ outpb, float* __restrict__ ze, int br0) {
  __shared__ __align__(16) float As[16][132];
  __shared__ __align__(16) float Ws[16][36];
  __shared__ __align__(16) float Cs[128][36];
  const int tid = threadIdx.x;
  const int b  = blockIdx.y;
  const int t0 = blockIdx.x * 128;
  const int br = br0 + (b >> 5);
  const float* W = outpW + (size_t)br * EE * HH;
  float acc[4][4] = {};
  const int ti = tid & 31, ni = tid >> 5;
  for (int k0 = 0; k0 < HH; k0 += 16) {
    __syncthreads();
    {
      int i = tid >> 1, kq = (tid & 1) * 8;
      const float* src = h + ((size_t)b * TT + t0 + i) * HH + k0 + kq;
      float4 a0 = *(const float4*)src;
      float4 a1 = *(const float4*)(src + 4);
      As[kq+0][i]=a0.x; As[kq+1][i]=a0.y; As[kq+2][i]=a0.z; As[kq+3][i]=a0.w;
      As[kq+4][i]=a1.x; As[kq+5][i]=a1.y; As[kq+6][i]=a1.z; As[kq+7][i]=a1.w;
    }
    for (int idx = tid; idx < 512; idx += 256) {
      int jj = idx >> 4, kk = idx & 15;
      Ws[kk][jj] = W[(size_t)jj * HH + k0 + kk];
    }
    __syncthreads();
    #pragma unroll
    for (int kk = 0; kk < 16; ++kk) {
      float4 a = *(const float4*)&As[kk][ti * 4];
      float4 w = *(const float4*)&Ws[kk][ni * 4];
      acc[0][0] += a.x*w.x; acc[0][1] += a.x*w.y; acc[0][2] += a.x*w.z; acc[0][3] += a.x*w.w;
      acc[1][0] += a.y*w.x; acc[1][1] += a.y*w.y; acc[1][2] += a.y*w.z; acc[1][3] += a.y*w.w;
      acc[2][0] += a.z*w.x; acc[2][1] += a.z*w.y; acc[2][2] += a.z*w.z; acc[2][3] += a.z*w.w;
      acc[3][0] += a.w*w.x; acc[3][1] += a.w*w.y; acc[3][2] += a.w*w.z; acc[3][3] += a.w*w.w;
    }
  }
  __syncthreads();
  float bj[4];
  #pragma unroll
  for (int c = 0; c < 4; ++c) bj[c] = outpb[br * EE + ni*4 + c];
  #pragma unroll
  for (int r = 0; r < 4; ++r)
    #pragma unroll
    for (int c = 0; c < 4; ++c)
      Cs[ti*4+r][ni*4+c] = tanhf(acc[r][c] + bj[c]);
  __syncthreads();
  int i = tid >> 1, j16 = (tid & 1) * 16;
  float* dst = ze + (((size_t)(br0 * 32 + b)) * TT + t0 + i) * EE + j16;
  #pragma unroll
  for (int q = 0; q < 4; ++q)
    *(float4*)(dst + q*4) = *(float4*)&Cs[i][j16 + q*4];
}

// ---------------- K7: hyperbolic combine ----------------
__device__ __forceinline__ void mobius_add32(const float* x, const float* y, float* o) {
  float x2 = 0.f, y2 = 0.f, xy = 0.f;
  #pragma unroll
  for (int i = 0; i < 32; ++i) { x2 += x[i]*x[i]; y2 += y[i]*y[i]; xy += x[i]*y[i]; }
  float ca  = 1.f + 2.f*xy + y2;
  float cb  = 1.f - x2;
  float den = 1.f + 2.f*xy + x2*y2;
  float inv = 1.f / fmaxf(den, 1e-15f);
  #pragma unroll
  for (int i = 0; i < 32; ++i) o[i] = (ca*x[i] + cb*y[i]) * inv;
}

__global__ __launch_bounds__(256) void k_hyper(const float* __restrict__ ze,
                                               float* __restrict__ out) {
  int idx = blockIdx.x * 256 + threadIdx.x;
  int b = idx >> 10, t = idx & 1023;
  float v[4][32];
  #pragma unroll
  for (int br = 0; br < 4; ++br) {
    const float* p = ze + (((size_t)br * BB + b) * TT + t) * EE;
    float s = 0.f;
    #pragma unroll
    for (int e = 0; e < 32; ++e) { v[br][e] = p[e]; s += v[br][e]*v[br][e]; }
    float nr = sqrtf(fmaxf(s, 1e-15f));
    float sc = tanhf(nr) / nr;
    float s2 = 0.f;
    #pragma unroll
    for (int e = 0; e < 32; ++e) { v[br][e] *= sc; s2 += v[br][e]*v[br][e]; }
    float n2 = sqrtf(fmaxf(s2, 1e-15f));
    if (n2 > 0.996f) {
      float sc2 = 0.996f / n2;
      #pragma unroll
      for (int e = 0; e < 32; ++e) v[br][e] *= sc2;
    }
    float* o = out + (((size_t)br * BB + b) * TT + t) * EE;
    #pragma unroll
    for (int e = 0; e < 32; ++e) o[e] = v[br][e];
  }
  float m1[32], m2[32];
  mobius_add32(v[1], v[2], m1);
  mobius_add32(v[0], m1, m2);
  mobius_add32(m2, v[3], m1);
  float s = 0.f;
  #pragma unroll
  for (int e = 0; e < 32; ++e) s += m1[e]*m1[e];
  float n = sqrtf(fmaxf(s, 1e-15f));
  if (n > 0.996f) {
    float sc = 0.996f / n;
    #pragma unroll
    for (int e = 0; e < 32; ++e) m1[e] *= sc;
  }
  float* o = out + (((size_t)4 * BB + b) * TT + t) * EE;
  #pragma unroll
  for (int e = 0; e < 32; ++e) o[e] = m1[e];
}

// ---------------- host ----------------
extern "C" void kernel_launch(void* const* d_in, const int* in_sizes, int n_in,
                              void* d_out, int out_size, void* d_ws, size_t ws_size,
                              hipStream_t stream) {
  const float* xs0 = (const float*)d_in[0];
  const float* xs1 = (const float*)d_in[1];
  const float* xs2 = (const float*)d_in[2];
  const float* xs3 = (const float*)d_in[3];
  const float* inpW   = (const float*)d_in[4];
  const float* inpb   = (const float*)d_in[5];
  const float* iprojW = (const float*)d_in[6];
  const float* convW  = (const float*)d_in[7];
  const float* convb  = (const float*)d_in[8];
  const float* xprojW = (const float*)d_in[9];
  const float* dtW    = (const float*)d_in[10];
  const float* dtb    = (const float*)d_in[11];
  const float* A_log  = (const float*)d_in[12];
  const float* D_skip = (const float*)d_in[13];
  const float* outW   = (const float*)d_in[14];
  const float* outpW  = (const float*)d_in[15];
  const float* outpb  = (const float*)d_in[16];
  float* out = (float*)d_out;
  float* ws  = (float*)d_ws;

  const size_t zeF = (size_t)4 * BB * TT * EE;
  // per fused batch row: h 65536 + xr/zb/u/dt 4*131072 + Bm/Cm 2*16384 + sdt 2048
  const size_t perBl = 65536 + 4 * 131072 + 2 * 16384 + 2048;
  auto needBytes = [&](int NB) { return (zeF + (size_t)NB * 32 * perBl) * 4; };
  int NB = 4;
  if (needBytes(4) > ws_size) NB = 2;
  if (NB == 2 && needBytes(2) > ws_size) NB = 1;
  const int nbl = NB * 32;

  float* ze = ws;
  float* h  = ze + zeF;
  float* xr = h  + (size_t)nbl * 65536;
  float* zb = xr + (size_t)nbl * 131072;
  float* u  = zb + (size_t)nbl * 131072;
  float* dt = u  + (size_t)nbl * 131072;
  float* Bm = dt + (size_t)nbl * 131072;
  float* Cm = Bm + (size_t)nbl * 16384;
  float* sdt = Cm + (size_t)nbl * 16384;
  float* g  = xr;   // alias: xr dead after k_xdbl, reused as y buffer
  float* Hloc = h;  // alias: h dead between k_xz (reads) and k_out (writes)

  for (int br0 = 0; br0 < 4; br0 += NB) {
    for (int l = 0; l < LL; ++l) {
      k_xz   <<<dim3(16, nbl), 256, 0, stream>>>(xs0, xs1, xs2, xs3, h, iprojW,
                                                 inpW, inpb, xr, zb, br0, l);
      k_xdbl <<<dim3(16, nbl), 256, 0, stream>>>(xr, convW, convb, xprojW, dtW, dtb,
                                                 u, dt, Bm, Cm, br0, l);
      k_scan1<<<nbl * 32, 256, 0, stream>>>(dt, u, Bm, Cm, A_log, D_skip,
                                            Hloc, g, sdt, br0, l);
      k_scan2<<<nbl * 60, 256, 0, stream>>>(dt, Cm, A_log, Hloc, sdt, g, br0, l);
      k_out  <<<dim3(16, nbl), 256, 0, stream>>>(g, zb, outW, h, br0, l);
    }
    k_ze<<<dim3(8, nbl), 256, 0, stream>>>(h, outpW, outpb, ze, br0);
  }
  k_hyper<<<BB * TT / 256, 256, 0, stream>>>(ze, out);
}

// Round 15
// 984.103 us; speedup vs baseline: 1.2817x; 1.0160x over previous
//
#include <hip/hip_runtime.h>
#include <math.h>

#define TT 1024
#define DIN 128
#define HH 64
#define NN 16
#define EE 32
#define LL 3
#define BB 32

__device__ __forceinline__ float siluf(float x) { return x / (1.f + __expf(-x)); }

typedef __attribute__((ext_vector_type(8))) short bf16x8;
typedef __attribute__((ext_vector_type(4))) float f32x4;

// split fp32 into bf16 hi + bf16 lo (truncation; a ~= hi + lo, err ~2^-16 rel)
__device__ __forceinline__ void split2(float x, ushort& hi, ushort& lo) {
  unsigned u = __float_as_uint(x);
  hi = (ushort)(u >> 16);
  float rem = x - __uint_as_float((u >> 16) << 16);
  lo = (ushort)(__float_as_uint(rem) >> 16);
}

// ---------------- K1: xz = h @ inW^T via split-bf16 MFMA ----------------
// A-tile (h) staged+split ONCE per block; loops over the 4 n-tiles of W.
// l==0: A-tile computed on the fly from x*inpW+inpb (k_init folded in).
__global__ __launch_bounds__(256) void k_xz(
    const float* __restrict__ x0, const float* __restrict__ x1,
    const float* __restrict__ x2, const float* __restrict__ x3,
    const float* __restrict__ h, const float* __restrict__ inprojW,
    const float* __restrict__ inpW, const float* __restrict__ inpb,
    float* __restrict__ xr, float* __restrict__ zb, int br0, int l) {
  __shared__ __align__(16) ushort Hh[64][72], Hl[64][72];  // h tile [t][k]
  __shared__ __align__(16) ushort Wh[64][72], Wl[64][72];  // W tile [n][k]
  const int tid = threadIdx.x;
  const int b  = blockIdx.y;
  const int t0 = blockIdx.x * 64;
  const int br = br0 + (b >> 5);
  const float* Hg = h + ((size_t)b * TT + t0) * HH;
  const int row = tid >> 2, c0 = (tid & 3) * 16;
  {
    float xv = 0.f;
    if (l == 0) {
      int bb = b & 31;
      const float* xp = (br == 0) ? x0 : (br == 1) ? x1 : (br == 2) ? x2 : x3;
      xv = xp[bb * TT + t0 + row];
    }
    #pragma unroll
    for (int q = 0; q < 4; ++q) {
      float4 hv;
      if (l == 0) {
        float4 w4 = *(const float4*)(inpW + br * HH + c0 + q * 4);
        float4 b4 = *(const float4*)(inpb + br * HH + c0 + q * 4);
        hv.x = xv * w4.x + b4.x; hv.y = xv * w4.y + b4.y;
        hv.z = xv * w4.z + b4.z; hv.w = xv * w4.w + b4.w;
      } else {
        hv = *(const float4*)(Hg + (size_t)row * HH + c0 + q * 4);
      }
      ushort h0,h1,h2,h3,l0,l1,l2,l3;
      split2(hv.x,h0,l0); split2(hv.y,h1,l1); split2(hv.z,h2,l2); split2(hv.w,h3,l3);
      *(ushort4*)&Hh[row][c0 + q*4] = make_ushort4(h0,h1,h2,h3);
      *(ushort4*)&Hl[row][c0 + q*4] = make_ushort4(l0,l1,l2,l3);
    }
  }
  const int wave = tid >> 6, lane = tid & 63;
  const int quad = lane >> 4, l16 = lane & 15;
  const int nsub = (wave & 1) * 32, tsub = (wave >> 1) * 32;
  for (int n0 = 0; n0 < 2 * DIN; n0 += 64) {
    const float* Wg = inprojW + (size_t)((br * LL + l) * 2 * DIN + n0) * HH;
    {
      #pragma unroll
      for (int q = 0; q < 4; ++q) {
        float4 wv = *(const float4*)(Wg + (size_t)row * HH + c0 + q * 4);
        ushort h0,h1,h2,h3,l0,l1,l2,l3;
        split2(wv.x,h0,l0); split2(wv.y,h1,l1); split2(wv.z,h2,l2); split2(wv.w,h3,l3);
        *(ushort4*)&Wh[row][c0 + q*4] = make_ushort4(h0,h1,h2,h3);
        *(ushort4*)&Wl[row][c0 + q*4] = make_ushort4(l0,l1,l2,l3);
      }
    }
    __syncthreads();
    f32x4 acc[2][2] = {};   // [n-frag][t-frag]
    #pragma unroll
    for (int k0 = 0; k0 < 64; k0 += 32) {
      bf16x8 Ah[2], Al[2], Bh[2], Bl[2];
      #pragma unroll
      for (int i = 0; i < 2; ++i) {
        Ah[i] = *(const bf16x8*)&Wh[nsub + i*16 + l16][k0 + quad*8];
        Al[i] = *(const bf16x8*)&Wl[nsub + i*16 + l16][k0 + quad*8];
        Bh[i] = *(const bf16x8*)&Hh[tsub + i*16 + l16][k0 + quad*8];
        Bl[i] = *(const bf16x8*)&Hl[tsub + i*16 + l16][k0 + quad*8];
      }
      #pragma unroll
      for (int i = 0; i < 2; ++i)
        #pragma unroll
        for (int j = 0; j < 2; ++j) {
          acc[i][j] = __builtin_amdgcn_mfma_f32_16x16x32_bf16(Ah[i], Bh[j], acc[i][j], 0, 0, 0);
          acc[i][j] = __builtin_amdgcn_mfma_f32_16x16x32_bf16(Ah[i], Bl[j], acc[i][j], 0, 0, 0);
          acc[i][j] = __builtin_amdgcn_mfma_f32_16x16x32_bf16(Al[i], Bh[j], acc[i][j], 0, 0, 0);
        }
    }
    // D layout: col(t) = lane&15, row(n) = quad*4 + reg
    #pragma unroll
    for (int i = 0; i < 2; ++i) {
      #pragma unroll
      for (int r = 0; r < 4; ++r) {
        int n = n0 + nsub + i*16 + quad*4 + r;
        float* dst = (n < DIN) ? (xr + ((size_t)b * DIN + n) * TT)
                               : (zb + ((size_t)b * DIN + (n - DIN)) * TT);
        #pragma unroll
        for (int j = 0; j < 2; ++j)
          dst[t0 + tsub + j*16 + l16] = acc[i][j][r];
      }
    }
    __syncthreads();  // protect Wh/Wl before next n-tile restages
  }
}

// ---- K3: fused conv+silu into x_dbl GEMM (split-bf16 MFMA); writes u; dt epilogue ----
// (R9/R10 measured-good version: fp32 W tile, in-register splits)
__global__ __launch_bounds__(256) void k_xdbl(
    const float* __restrict__ xr, const float* __restrict__ convW,
    const float* __restrict__ convb, const float* __restrict__ xprojW,
    const float* __restrict__ dtW, const float* __restrict__ dtb,
    float* __restrict__ u, float* __restrict__ dt,
    float* __restrict__ Bm, float* __restrict__ Cm,
    int br0, int l) {
  __shared__ __align__(16) float Xr[16][72];
  __shared__ __align__(16) float As2[32][68];  // u tile, fp32 [k][t]
  __shared__ __align__(16) float Ws2[32][48];  // W tile, fp32 [k][n], n>=36 zero
  __shared__ __align__(16) float Xs[40][68];
  const int tid = threadIdx.x;
  const int b  = blockIdx.y;
  const int t0 = blockIdx.x * 64;
  const int br = br0 + (b >> 5);
  const float* W = xprojW + (size_t)((br * LL + l) * 36) * DIN;
  const int rowk = tid >> 4, c4 = tid & 15;
  const int wave = tid >> 6, lane = tid & 63;
  const int quad = lane >> 4, l16 = lane & 15;
  const int tw = wave * 16;            // wave's t-offset
  f32x4 acc[3] = {};                   // 3 n-frags (n = 0..47), t = tw..tw+15
  for (int k0 = 0; k0 < DIN; k0 += 32) {
    #pragma unroll
    for (int ks = 0; ks < 32; ks += 16) {
      __syncthreads();
      {
        const float* src = xr + ((size_t)b * DIN + k0 + ks + rowk) * TT + t0;
        *(float4*)&Xr[rowk][4 + c4 * 4] = *(const float4*)(src + c4 * 4);
        if (tid < 16) {
          float4 hv = make_float4(0.f, 0.f, 0.f, 0.f);
          if (t0 > 0) hv = *(const float4*)(xr + ((size_t)b * DIN + k0 + ks + tid) * TT + t0 - 4);
          *(float4*)&Xr[tid][0] = hv;
        }
      }
      __syncthreads();
      {
        int d = k0 + ks + rowk;
        const float* w = convW + (size_t)((br * LL + l) * DIN + d) * 4;
        float w0 = w[0], w1 = w[1], w2 = w[2], w3 = w[3];
        float cb = convb[(br * LL + l) * DIN + d];
        int i0 = c4 * 4;
        float o[4];
        #pragma unroll
        for (int q = 0; q < 4; ++q) {
          int j = i0 + q;
          float a = Xr[rowk][j+1]*w0 + Xr[rowk][j+2]*w1 + Xr[rowk][j+3]*w2 + Xr[rowk][j+4]*w3 + cb;
          o[q] = siluf(a);
        }
        float4 uo = make_float4(o[0], o[1], o[2], o[3]);
        *(float4*)&As2[ks + rowk][i0] = uo;
        *(float4*)(u + ((size_t)b * DIN + d) * TT + t0 + i0) = uo;
      }
    }
    // stage W chunk [32 k][48 n] (n >= 36 zeroed)
    for (int idx = tid; idx < 1536; idx += 256) {
      int jj = idx >> 5, kk = idx & 31;
      Ws2[kk][jj] = (jj < 36) ? W[(size_t)jj * DIN + k0 + kk] : 0.f;
    }
    __syncthreads();
    // MFMA: A = W (rows n), B = u (rows t); k = quad*8 + 0..7
    ushort bh[8], bl[8];
    #pragma unroll
    for (int j = 0; j < 8; ++j) {
      float v = As2[quad * 8 + j][tw + l16];
      split2(v, bh[j], bl[j]);
    }
    bf16x8 Bh = *(bf16x8*)bh, Bl = *(bf16x8*)bl;
    #pragma unroll
    for (int nf = 0; nf < 3; ++nf) {
      ushort wh[8], wl[8];
      #pragma unroll
      for (int j = 0; j < 8; ++j) {
        float v = Ws2[quad * 8 + j][nf * 16 + l16];
        split2(v, wh[j], wl[j]);
      }
      bf16x8 Wh = *(bf16x8*)wh, Wl = *(bf16x8*)wl;
      acc[nf] = __builtin_amdgcn_mfma_f32_16x16x32_bf16(Wh, Bh, acc[nf], 0, 0, 0);
      acc[nf] = __builtin_amdgcn_mfma_f32_16x16x32_bf16(Wh, Bl, acc[nf], 0, 0, 0);
      acc[nf] = __builtin_amdgcn_mfma_f32_16x16x32_bf16(Wl, Bh, acc[nf], 0, 0, 0);
    }
  }
  __syncthreads();
  // D layout: col(t) = l16, row(n) = quad*4 + r  ->  Xs[n][t]
  #pragma unroll
  for (int nf = 0; nf < 3; ++nf) {
    #pragma unroll
    for (int r = 0; r < 4; ++r) {
      int n = nf * 16 + quad * 4 + r;
      if (n < 40) Xs[n][tw + l16] = acc[nf][r];
    }
  }
  __syncthreads();
  {
    int n = tid >> 4, i0 = (tid & 15) * 4;
    *(float4*)(Bm + ((size_t)b * NN + n) * TT + t0 + i0) = *(float4*)&Xs[4 + n][i0];
    *(float4*)(Cm + ((size_t)b * NN + n) * TT + t0 + i0) = *(float4*)&Xs[20 + n][i0];
  }
  {
    int d = tid >> 1, half = tid & 1;
    const float* wd = dtW + (size_t)((br * LL + l) * DIN + d) * 4;
    float w0 = wd[0], w1 = wd[1], w2 = wd[2], w3 = wd[3];
    float bias = dtb[(br * LL + l) * DIN + d];
    float* dtp = dt + ((size_t)b * DIN + d) * TT + t0 + half * 32;
    #pragma unroll
    for (int g8 = 0; g8 < 8; ++g8) {
      float o[4];
      #pragma unroll
      for (int q = 0; q < 4; ++q) {
        int i = half * 32 + g8 * 4 + q;
        float s = Xs[0][i]*w0 + Xs[1][i]*w1 + Xs[2][i]*w2 + Xs[3][i]*w3 + bias;
        float e = __expf(-fabsf(s));
        o[q] = fmaxf(s, 0.f) + __logf(1.f + e);
      }
      *(float4*)(dtp + g8*4) = make_float4(o[0], o[1], o[2], o[3]);
    }
  }
}

// ---- K4a: local chunk scan (chunk=64). Emits y_intra (g), Hloc, sdt (chunk dt-sums).
// Bl/Cl stride 66 (group stride 8 mod 32 banks -> conflict-free); float2 access width.
__global__ __launch_bounds__(256) void k_scan1(
    const float* __restrict__ dtc, const float* __restrict__ u,
    const float* __restrict__ Bm, const float* __restrict__ Cm,
    const float* __restrict__ A_log, const float* __restrict__ D_skip,
    float* __restrict__ Hloc, float* __restrict__ g, float* __restrict__ sdt,
    int br0, int l) {
  __shared__ __align__(16) float Bl[16][66];
  __shared__ __align__(16) float Cl[16][66];
  const int bx  = blockIdx.x;
  const int b   = bx >> 5;
  const int rem = bx & 31;
  const int c   = rem >> 1;
  const int dh  = rem & 1;
  const int tid = threadIdx.x;
  {
    int row = tid >> 4, cc = (tid & 15) * 4;
    float4 bv = *(const float4*)(Bm + ((size_t)b * NN + row) * TT + c * 64 + cc);
    *(float2*)&Bl[row][cc]     = make_float2(bv.x, bv.y);
    *(float2*)&Bl[row][cc + 2] = make_float2(bv.z, bv.w);
    float4 cv = *(const float4*)(Cm + ((size_t)b * NN + row) * TT + c * 64 + cc);
    *(float2*)&Cl[row][cc]     = make_float2(cv.x, cv.y);
    *(float2*)&Cl[row][cc + 2] = make_float2(cv.z, cv.w);
  }
  __syncthreads();
  const int d  = dh * 64 + (tid >> 2);
  const int n0 = (tid & 3) * 4;
  const int br = br0 + (b >> 5);
  const int wbase = (br * LL + l) * DIN + d;
  float Ac[4];
  #pragma unroll
  for (int j = 0; j < 4; ++j) Ac[j] = -__expf(A_log[(size_t)wbase * NN + n0 + j]);
  float Dp = D_skip[wbase];
  const float* dtp = dtc + ((size_t)b * DIN + d) * TT + c * 64;
  const float* up = u + ((size_t)b * DIN + d) * TT + c * 64;
  float* gp = g + ((size_t)b * DIN + d) * TT + c * 64;
  float hst[4] = {0.f, 0.f, 0.f, 0.f};
  float sd = 0.f;
  for (int t0 = 0; t0 < 64; t0 += 8) {
    float4 dq0 = *(const float4*)(dtp + t0);
    float4 dq1 = *(const float4*)(dtp + t0 + 4);
    float4 uq0 = *(const float4*)(up + t0);
    float4 uq1 = *(const float4*)(up + t0 + 4);
    float dts[8] = {dq0.x, dq0.y, dq0.z, dq0.w, dq1.x, dq1.y, dq1.z, dq1.w};
    float us[8]  = {uq0.x, uq0.y, uq0.z, uq0.w, uq1.x, uq1.y, uq1.z, uq1.w};
    float Bs[4][8], Cr[4][8];
    #pragma unroll
    for (int j = 0; j < 4; ++j) {
      float2 b0 = *(const float2*)&Bl[n0 + j][t0];
      float2 b1 = *(const float2*)&Bl[n0 + j][t0 + 2];
      float2 b2 = *(const float2*)&Bl[n0 + j][t0 + 4];
      float2 b3 = *(const float2*)&Bl[n0 + j][t0 + 6];
      Bs[j][0]=b0.x; Bs[j][1]=b0.y; Bs[j][2]=b1.x; Bs[j][3]=b1.y;
      Bs[j][4]=b2.x; Bs[j][5]=b2.y; Bs[j][6]=b3.x; Bs[j][7]=b3.y;
      float2 c0 = *(const float2*)&Cl[n0 + j][t0];
      float2 c1 = *(const float2*)&Cl[n0 + j][t0 + 2];
      float2 c2 = *(const float2*)&Cl[n0 + j][t0 + 4];
      float2 c3 = *(const float2*)&Cl[n0 + j][t0 + 6];
      Cr[j][0]=c0.x; Cr[j][1]=c0.y; Cr[j][2]=c1.x; Cr[j][3]=c1.y;
      Cr[j][4]=c2.x; Cr[j][5]=c2.y; Cr[j][6]=c3.x; Cr[j][7]=c3.y;
    }
    float yo[8];
    #pragma unroll
    for (int s = 0; s < 8; ++s) {
      float dtv = dts[s], uv = us[s];
      sd += dtv;
      float du = dtv * uv;
      float acc = 0.f;
      #pragma unroll
      for (int j = 0; j < 4; ++j) {
        float dA = __expf(dtv * Ac[j]);
        hst[j] = dA * hst[j] + du * Bs[j][s];
        acc += hst[j] * Cr[j][s];
      }
      acc += __shfl_xor(acc, 1, 4);
      acc += __shfl_xor(acc, 2, 4);
      yo[s] = acc + Dp * uv;
    }
    if ((tid & 3) == 0) {
      *(float4*)(gp + t0)     = make_float4(yo[0], yo[1], yo[2], yo[3]);
      *(float4*)(gp + t0 + 4) = make_float4(yo[4], yo[5], yo[6], yo[7]);
    }
  }
  *(float4*)(Hloc + (((size_t)b * DIN + d) * 16 + c) * 16 + n0) =
      make_float4(hst[0], hst[1], hst[2], hst[3]);
  if ((tid & 3) == 0) sdt[((size_t)b * DIN + d) * 16 + c] = sd;
}

// ---- K4c: combine (from Hloc + sdt) + parallel correction.
// Grid covers c in [1,15] only (c==0 needs no correction).
__global__ __launch_bounds__(256) void k_scan2(
    const float* __restrict__ dtc, const float* __restrict__ Cm,
    const float* __restrict__ A_log, const float* __restrict__ Hloc,
    const float* __restrict__ sdt, float* __restrict__ g, int br0, int l) {
  __shared__ __align__(16) float Cl[16][68];
  __shared__ __align__(16) float Dl[32][68];
  __shared__ __align__(16) float HinL[32][16];
  const int bx  = blockIdx.x;
  const int b   = bx / 60;
  const int rem = bx % 60;
  const int c   = (rem >> 2) + 1;   // 1..15
  const int dq  = rem & 3;
  const int tid = threadIdx.x;
  const int br  = br0 + (b >> 5);
  {
    int row = tid >> 4, cc = (tid & 15) * 4;
    *(float4*)&Cl[row][cc] = *(const float4*)(Cm + ((size_t)b * NN + row) * TT + c * 64 + cc);
  }
  const int dloc = tid >> 3, tg = tid & 7;
  const int d  = dq * 32 + dloc;
  // stage this block's dt chunk [32 d][64 t]
  {
    const float* dp = dtc + ((size_t)b * DIN + d) * TT + c * 64 + tg * 8;
    *(float4*)&Dl[dloc][tg * 8]     = *(const float4*)dp;
    *(float4*)&Dl[dloc][tg * 8 + 4] = *(const float4*)(dp + 4);
  }
  // combine phase: h_in for this chunk, threads = (dloc 32) x (n-pair 8)
  {
    int n0 = (tid & 7) * 2;
    int wbase = (br * LL + l) * DIN + d;
    float a0 = -__expf(A_log[(size_t)wbase * NN + n0]);
    float a1 = -__expf(A_log[(size_t)wbase * NN + n0 + 1]);
    float h0 = 0.f, h1 = 0.f;
    const float* sp  = sdt + ((size_t)b * DIN + d) * 16;
    const float* hlb = Hloc + ((size_t)b * DIN + d) * 256;
    for (int cc = 0; cc < c; ++cc) {
      float sdv = sp[cc];
      float2 hl = *(const float2*)(hlb + cc * 16 + n0);
      h0 = __expf(a0 * sdv) * h0 + hl.x;
      h1 = __expf(a1 * sdv) * h1 + hl.y;
    }
    HinL[dloc][n0] = h0;
    HinL[dloc][n0 + 1] = h1;
  }
  __syncthreads();
  // recompute cd for this thread's 8 t's (serial ascending, same order as scan1)
  float cd8[8];
  {
    float run = 0.f;
    for (int t = 0; t < tg * 8; ++t) run += Dl[dloc][t];
    #pragma unroll
    for (int s = 0; s < 8; ++s) { run += Dl[dloc][tg * 8 + s]; cd8[s] = run; }
  }
  const float* al = A_log + (size_t)((br * LL + l) * DIN + d) * NN;
  float Ac16[16];
  #pragma unroll
  for (int n = 0; n < 16; ++n) Ac16[n] = -__expf(al[n]);
  size_t off = ((size_t)b * DIN + d) * TT + c * 64 + tg * 8;
  float* gp = g + off;
  float4 y0 = *(float4*)gp;
  float4 y1 = *(float4*)(gp + 4);
  float y8[8] = {y0.x, y0.y, y0.z, y0.w, y1.x, y1.y, y1.z, y1.w};
  const int tbase = tg * 8;
  #pragma unroll
  for (int n = 0; n < 16; ++n) {
    float hv = HinL[dloc][n];
    float an = Ac16[n];
    #pragma unroll
    for (int s = 0; s < 8; ++s)
      y8[s] += Cl[n][tbase + s] * __expf(an * cd8[s]) * hv;
  }
  *(float4*)gp       = make_float4(y8[0], y8[1], y8[2], y8[3]);
  *(float4*)(gp + 4) = make_float4(y8[4], y8[5], y8[6], y8[7]);
}

// ---------------- K5: h = (y * silu(z)) @ outW^T via split-bf16 MFMA ----------------
__global__ __launch_bounds__(256) void k_out(
    const float* __restrict__ graw, const float* __restrict__ zb,
    const float* __restrict__ outW, float* __restrict__ h, int br0, int l) {
  __shared__ __align__(16) ushort Ah_[64][72], Al_[64][72];  // outW tile [hh][k]
  __shared__ __align__(16) ushort Bh_[64][72], Bl_[64][72];  // act tile [d][t]
  const int tid = threadIdx.x;
  const int b  = blockIdx.y;
  const int t0 = blockIdx.x * 64;
  const int br = br0 + (b >> 5);
  const float* Wg = outW + (size_t)((br * LL + l) * HH) * DIN;
  const int wave = tid >> 6, lane = tid & 63;
  const int quad = lane >> 4, l16 = lane & 15;
  const int hsub = (wave & 1) * 32, tsub = (wave >> 1) * 32;
  f32x4 acc[2][2] = {};   // [hh-frag][t-frag]
  for (int k0 = 0; k0 < DIN; k0 += 64) {
    __syncthreads();
    {
      int row = tid >> 2, c0 = (tid & 3) * 16;
      #pragma unroll
      for (int q = 0; q < 4; ++q) {
        float4 wv = *(const float4*)(Wg + (size_t)row * DIN + k0 + c0 + q * 4);
        ushort h0,h1,h2,h3,l0,l1,l2,l3;
        split2(wv.x,h0,l0); split2(wv.y,h1,l1); split2(wv.z,h2,l2); split2(wv.w,h3,l3);
        *(ushort4*)&Ah_[row][c0 + q*4] = make_ushort4(h0,h1,h2,h3);
        *(ushort4*)&Al_[row][c0 + q*4] = make_ushort4(l0,l1,l2,l3);
        size_t off = ((size_t)b * DIN + k0 + row) * TT + t0 + c0 + q * 4;
        float4 gv = *(const float4*)(graw + off);
        float4 zv = *(const float4*)(zb + off);
        float a0 = gv.x * siluf(zv.x), a1 = gv.y * siluf(zv.y);
        float a2 = gv.z * siluf(zv.z), a3 = gv.w * siluf(zv.w);
        split2(a0,h0,l0); split2(a1,h1,l1); split2(a2,h2,l2); split2(a3,h3,l3);
        *(ushort4*)&Bh_[row][c0 + q*4] = make_ushort4(h0,h1,h2,h3);
        *(ushort4*)&Bl_[row][c0 + q*4] = make_ushort4(l0,l1,l2,l3);
      }
    }
    __syncthreads();
    #pragma unroll
    for (int kk = 0; kk < 64; kk += 32) {
      bf16x8 Ahf[2], Alf[2], Bhf[2], Blf[2];
      #pragma unroll
      for (int i = 0; i < 2; ++i) {
        Ahf[i] = *(const bf16x8*)&Ah_[hsub + i*16 + l16][kk + quad*8];
        Alf[i] = *(const bf16x8*)&Al_[hsub + i*16 + l16][kk + quad*8];
        Bhf[i] = *(const bf16x8*)&Bh_[tsub + i*16 + l16][kk + quad*8];
        Blf[i] = *(const bf16x8*)&Bl_[tsub + i*16 + l16][kk + quad*8];
      }
      #pragma unroll
      for (int i = 0; i < 2; ++i)
        #pragma unroll
        for (int j = 0; j < 2; ++j) {
          acc[i][j] = __builtin_amdgcn_mfma_f32_16x16x32_bf16(Ahf[i], Bhf[j], acc[i][j], 0, 0, 0);
          acc[i][j] = __builtin_amdgcn_mfma_f32_16x16x32_bf16(Ahf[i], Blf[j], acc[i][j], 0, 0, 0);
          acc[i][j] = __builtin_amdgcn_mfma_f32_16x16x32_bf16(Alf[i], Bhf[j], acc[i][j], 0, 0, 0);
        }
    }
  }
  #pragma unroll
  for (int i = 0; i < 2; ++i) {
    int hh0 = hsub + i*16 + quad*4;
    #pragma unroll
    for (int j = 0; j < 2; ++j) {
      int t = t0 + tsub + j*16 + l16;
      *(f32x4*)(h + ((size_t)b * TT + t) * HH + hh0) = acc[i][j];
    }
  }
}

// ---------------- K6: ze = tanh(h @ outp_W^T + outp_b) ----------------
__global__ __launch_bounds__(256) void k_ze(
    const float* __restrict__ h, const float* __restrict__ outpW,
    const float* __restrict__ outpb, float* __restrict__ ze, int br0) {
  __shared__ __align__(16) float As[16][132];
  __shared__ __align__(16) float Ws[16][36];
  __shared__ __align__(16) float Cs[128][36];
  const int tid = threadIdx.x;
  const int b  = blockIdx.y;
  const int t0 = blockIdx.x * 128;
  const int br = br0 + (b >> 5);
  const float* W = outpW + (size_t)br * EE * HH;
  float acc[4][4] = {};
  const int ti = tid & 31, ni = tid >> 5;
  for (int k0 = 0; k0 < HH; k0 += 16) {
    __syncthreads();
    {
      int i = tid >> 1, kq = (tid & 1) * 8;
      const float* src = h + ((size_t)b * TT + t0 + i) * HH + k0 + kq;
      float4 a0 = *(const float4*)src;
      float4 a1 = *(const float4*)(src + 4);
      As[kq+0][i]=a0.x; As[kq+1][i]=a0.y; As[kq+2][i]=a0.z; As[kq+3][i]=a0.w;
      As[kq+4][i]=a1.x; As[kq+5][i]=a1.y; As[kq+6][i]=a1.z; As[kq+7][i]=a1.w;
    }
    for (int idx = tid; idx < 512; idx += 256) {
      int jj = idx >> 4, kk = idx & 15;
      Ws[kk][jj] = W[(size_t)jj * HH + k0 + kk];
    }
    __syncthreads();
    #pragma unroll
    for (int kk = 0; kk < 16; ++kk) {
      float4 a = *(const float4*)&As[kk][ti * 4];
      float4 w = *(const float4*)&Ws[kk][ni * 4];
      acc[0][0] += a.x*w.x; acc[0][1] += a.x*w.y; acc[0][2] += a.x*w.z; acc[0][3] += a.x*w.w;
      acc[1][0] += a.y*w.x; acc[1][1] += a.y*w.y; acc[1][2] += a.y*w.z; acc[1][3] += a.y*w.w;
      acc[2][0] += a.z*w.x; acc[2][1] += a.z*w.y; acc[2][2] += a.z*w.z; acc[2][3] += a.z*w.w;
      acc[3][0] += a.w*w.x; acc[3][1] += a.w*w.y; acc[3][2] += a.w*w.z; acc[3][3] += a.w*w.w;
    }
  }
  __syncthreads();
  float bj[4];
  #pragma unroll
  for (int c = 0; c < 4; ++c) bj[c] = outpb[br * EE + ni*4 + c];
  #pragma unroll
  for (int r = 0; r < 4; ++r)
    #pragma unroll
    for (int c = 0; c < 4; ++c)
      Cs[ti*4+r][ni*4+c] = tanhf(acc[r][c] + bj[c]);
  __syncthreads();
  int i = tid >> 1, j16 = (tid & 1) * 16;
  float* dst = ze + (((size_t)(br0 * 32 + b)) * TT + t0 + i) * EE + j16;
  #pragma unroll
  for (int q = 0; q < 4; ++q)
    *(float4*)(dst + q*4) = *(float4*)&Cs[i][j16 + q*4];
}

// ---------------- K7: hyperbolic combine ----------------
__device__ __forceinline__ void mobius_add32(const float* x, const float* y, float* o) {
  float x2 = 0.f, y2 = 0.f, xy = 0.f;
  #pragma unroll
  for (int i = 0; i < 32; ++i) { x2 += x[i]*x[i]; y2 += y[i]*y[i]; xy += x[i]*y[i]; }
  float ca  = 1.f + 2.f*xy + y2;
  float cb  = 1.f - x2;
  float den = 1.f + 2.f*xy + x2*y2;
  float inv = 1.f / fmaxf(den, 1e-15f);
  #pragma unroll
  for (int i = 0; i < 32; ++i) o[i] = (ca*x[i] + cb*y[i]) * inv;
}

__global__ __launch_bounds__(256) void k_hyper(const float* __restrict__ ze,
                                               float* __restrict__ out) {
  int idx = blockIdx.x * 256 + threadIdx.x;
  int b = idx >> 10, t = idx & 1023;
  float v[4][32];
  #pragma unroll
  for (int br = 0; br < 4; ++br) {
    const float* p = ze + (((size_t)br * BB + b) * TT + t) * EE;
    float s = 0.f;
    #pragma unroll
    for (int e = 0; e < 32; ++e) { v[br][e] = p[e]; s += v[br][e]*v[br][e]; }
    float nr = sqrtf(fmaxf(s, 1e-15f));
    float sc = tanhf(nr) / nr;
    float s2 = 0.f;
    #pragma unroll
    for (int e = 0; e < 32; ++e) { v[br][e] *= sc; s2 += v[br][e]*v[br][e]; }
    float n2 = sqrtf(fmaxf(s2, 1e-15f));
    if (n2 > 0.996f) {
      float sc2 = 0.996f / n2;
      #pragma unroll
      for (int e = 0; e < 32; ++e) v[br][e] *= sc2;
    }
    float* o = out + (((size_t)br * BB + b) * TT + t) * EE;
    #pragma unroll
    for (int e = 0; e < 32; ++e) o[e] = v[br][e];
  }
  float m1[32], m2[32];
  mobius_add32(v[1], v[2], m1);
  mobius_add32(v[0], m1, m2);
  mobius_add32(m2, v[3], m1);
  float s = 0.f;
  #pragma unroll
  for (int e = 0; e < 32; ++e) s += m1[e]*m1[e];
  float n = sqrtf(fmaxf(s, 1e-15f));
  if (n > 0.996f) {
    float sc = 0.996f / n;
    #pragma unroll
    for (int e = 0; e < 32; ++e) m1[e] *= sc;
  }
  float* o = out + (((size_t)4 * BB + b) * TT + t) * EE;
  #pragma unroll
  for (int e = 0; e < 32; ++e) o[e] = m1[e];
}

// ---------------- host ----------------
extern "C" void kernel_launch(void* const* d_in, const int* in_sizes, int n_in,
                              void* d_out, int out_size, void* d_ws, size_t ws_size,
                              hipStream_t stream) {
  const float* xs0 = (const float*)d_in[0];
  const float* xs1 = (const float*)d_in[1];
  const float* xs2 = (const float*)d_in[2];
  const float* xs3 = (const float*)d_in[3];
  const float* inpW   = (const float*)d_in[4];
  const float* inpb   = (const float*)d_in[5];
  const float* iprojW = (const float*)d_in[6];
  const float* convW  = (const float*)d_in[7];
  const float* convb  = (const float*)d_in[8];
  const float* xprojW = (const float*)d_in[9];
  const float* dtW    = (const float*)d_in[10];
  const float* dtb    = (const float*)d_in[11];
  const float* A_log  = (const float*)d_in[12];
  const float* D_skip = (const float*)d_in[13];
  const float* outW   = (const float*)d_in[14];
  const float* outpW  = (const float*)d_in[15];
  const float* outpb  = (const float*)d_in[16];
  float* out = (float*)d_out;
  float* ws  = (float*)d_ws;

  const size_t zeF = (size_t)4 * BB * TT * EE;
  // per fused batch row: h 65536 + xr/zb/u/dt 4*131072 + Bm/Cm 2*16384 + sdt 2048
  const size_t perBl = 65536 + 4 * 131072 + 2 * 16384 + 2048;
  auto needBytes = [&](int NB) { return (zeF + (size_t)NB * 32 * perBl) * 4; };
  int NB = 4;
  if (needBytes(4) > ws_size) NB = 2;
  if (NB == 2 && needBytes(2) > ws_size) NB = 1;
  const int nbl = NB * 32;

  float* ze = ws;
  float* h  = ze + zeF;
  float* xr = h  + (size_t)nbl * 65536;
  float* zb = xr + (size_t)nbl * 131072;
  float* u  = zb + (size_t)nbl * 131072;
  float* dt = u  + (size_t)nbl * 131072;
  float* Bm = dt + (size_t)nbl * 131072;
  float* Cm = Bm + (size_t)nbl * 16384;
  float* sdt = Cm + (size_t)nbl * 16384;
  float* g  = xr;   // alias: xr dead after k_xdbl, reused as y buffer
  float* Hloc = h;  // alias: h dead between k_xz (reads) and k_out (writes)

  for (int br0 = 0; br0 < 4; br0 += NB) {
    for (int l = 0; l < LL; ++l) {
      k_xz   <<<dim3(16, nbl), 256, 0, stream>>>(xs0, xs1, xs2, xs3, h, iprojW,
                                                 inpW, inpb, xr, zb, br0, l);
      k_xdbl <<<dim3(16, nbl), 256, 0, stream>>>(xr, convW, convb, xprojW, dtW, dtb,
                                                 u, dt, Bm, Cm, br0, l);
      k_scan1<<<nbl * 32, 256, 0, stream>>>(dt, u, Bm, Cm, A_log, D_skip,
                                            Hloc, g, sdt, br0, l);
      k_scan2<<<nbl * 60, 256, 0, stream>>>(dt, Cm, A_log, Hloc, sdt, g, br0, l);
      k_out  <<<dim3(16, nbl), 256, 0, stream>>>(g, zb, outW, h, br0, l);
    }
    k_ze<<<dim3(8, nbl), 256, 0, stream>>>(h, outpW, outpb, ze, br0);
  }
  k_hyper<<<BB * TT / 256, 256, 0, stream>>>(ze, out);
}